// Round 2
// baseline (295.819 us; speedup 1.0000x reference)
//
#include <hip/hip_runtime.h>
#include <hip/hip_bf16.h>

typedef __attribute__((ext_vector_type(8))) short short8;
typedef __attribute__((ext_vector_type(4))) float f32x4;

#define INV_TEMP 14.285714285714286f
#define LOGIT_MAX 14.2857143f

__device__ __forceinline__ float dot4f(const float4 a, const float4 b) {
  return a.x * b.x + a.y * b.y + a.z * b.z + a.w * b.w;
}

__device__ __forceinline__ ushort bf16c(float f) {
  uint u = __float_as_uint(f);
  uint r = (u + 0x7fffu + ((u >> 16) & 1u)) >> 16;
  return (ushort)r;
}

__device__ __forceinline__ uint pk2(float a, float b) {
  return (uint)bf16c(a) | ((uint)bf16c(b) << 16);
}

// ---------- pool = l2norm(encoded.reshape(2048,256)) -> bf16 ----------
__global__ __launch_bounds__(256) void pool_norm_kernel(
    const float* __restrict__ enc, ushort* __restrict__ poolb) {
  const int tid = threadIdx.x;
  const int grp = tid >> 4, lane = tid & 15;
  const int r = blockIdx.x * 16 + grp;  // 0..2047
  const float* src = enc + (size_t)r * 256;
  float4 v0 = *(const float4*)(src + lane * 4);
  float4 v1 = *(const float4*)(src + 64 + lane * 4);
  float4 v2 = *(const float4*)(src + 128 + lane * 4);
  float4 v3 = *(const float4*)(src + 192 + lane * 4);
  float ss = dot4f(v0, v0) + dot4f(v1, v1) + dot4f(v2, v2) + dot4f(v3, v3);
#pragma unroll
  for (int m = 1; m <= 8; m <<= 1) ss += __shfl_xor(ss, m);
  const float inv = rsqrtf(ss);
  ushort* dst = poolb + (size_t)r * 256;
  ushort4 o;
  o = make_ushort4(bf16c(v0.x * inv), bf16c(v0.y * inv), bf16c(v0.z * inv), bf16c(v0.w * inv));
  *(ushort4*)(dst + lane * 4) = o;
  o = make_ushort4(bf16c(v1.x * inv), bf16c(v1.y * inv), bf16c(v1.z * inv), bf16c(v1.w * inv));
  *(ushort4*)(dst + 64 + lane * 4) = o;
  o = make_ushort4(bf16c(v2.x * inv), bf16c(v2.y * inv), bf16c(v2.z * inv), bf16c(v2.w * inv));
  *(ushort4*)(dst + 128 + lane * 4) = o;
  o = make_ushort4(bf16c(v3.x * inv), bf16c(v3.y * inv), bf16c(v3.z * inv), bf16c(v3.w * inv));
  *(ushort4*)(dst + 192 + lane * 4) = o;
}

// ---------- z_hat[k] = ctx_rows @ W[k]^T via bf16 MFMA, fp32 out ----------
// Tile: BM=64, BN=128, BK=32. 256 threads = 4 waves (2x2), wave tile 32x64.
__global__ __launch_bounds__(256) void zhat_gemm_kernel(
    const float* __restrict__ ctx, const float* __restrict__ W,
    float* __restrict__ Z) {
  const int kk = blockIdx.z;
  const int Tk = 255 - kk, Nk = 8 * Tk;
  const int rowbase = blockIdx.y * 64;
  if (rowbase >= Nk) return;
  const int colbase = blockIdx.x * 128;

  __shared__ ushort As[64 * 40];   // row stride 40 bf16 (pad 8)
  __shared__ ushort Bs[128 * 40];

  const int tid = threadIdx.x;
  // A loader: row = t&63, kseg = (t>>6)*8 (8 floats per thread per step)
  const int arow = tid & 63;
  const int akseg = (tid >> 6) * 8;
  int n = rowbase + arow;
  if (n >= Nk) n = Nk - 1;  // clamp (valid memory; result rows discarded)
  const int bb = n / Tk, tt = n - bb * Tk;
  const float* aptr = ctx + ((size_t)(bb * 256 + tt)) * 512 + akseg;
  // B loader: row = t&127, kseg = (t>>7)*16 (16 floats per thread per step)
  const int brow = tid & 127;
  const int bkseg = (tid >> 7) * 16;
  const float* bptr = W + ((size_t)kk * 256 + colbase + brow) * 512 + bkseg;

  const int wid = tid >> 6, lane = tid & 63;
  const int wm = wid >> 1, wn = wid & 1;
  const int l15 = lane & 15, l16 = lane >> 4;

  f32x4 acc[2][4];
#pragma unroll
  for (int i = 0; i < 2; ++i)
#pragma unroll
    for (int j = 0; j < 4; ++j) acc[i][j] = (f32x4){0.f, 0.f, 0.f, 0.f};

  const ushort* aread = &As[(wm * 32 + l15) * 40 + l16 * 8];
  const ushort* bread = &Bs[(wn * 64 + l15) * 40 + l16 * 8];

  for (int k0 = 0; k0 < 512; k0 += 32) {
    const float4 a0 = *(const float4*)(aptr + k0);
    const float4 a1 = *(const float4*)(aptr + k0 + 4);
    const float4 b0 = *(const float4*)(bptr + k0);
    const float4 b1 = *(const float4*)(bptr + k0 + 4);
    const float4 b2 = *(const float4*)(bptr + k0 + 8);
    const float4 b3 = *(const float4*)(bptr + k0 + 12);
    __syncthreads();
    {
      uint4 w0 = make_uint4(pk2(a0.x, a0.y), pk2(a0.z, a0.w), pk2(a1.x, a1.y), pk2(a1.z, a1.w));
      *(uint4*)&As[arow * 40 + akseg] = w0;
      uint4 w1 = make_uint4(pk2(b0.x, b0.y), pk2(b0.z, b0.w), pk2(b1.x, b1.y), pk2(b1.z, b1.w));
      *(uint4*)&Bs[brow * 40 + bkseg] = w1;
      uint4 w2 = make_uint4(pk2(b2.x, b2.y), pk2(b2.z, b2.w), pk2(b3.x, b3.y), pk2(b3.z, b3.w));
      *(uint4*)&Bs[brow * 40 + bkseg + 8] = w2;
    }
    __syncthreads();
    short8 bf[4];
#pragma unroll
    for (int nb = 0; nb < 4; ++nb) bf[nb] = *(const short8*)(bread + nb * 16 * 40);
#pragma unroll
    for (int mb = 0; mb < 2; ++mb) {
      short8 af = *(const short8*)(aread + mb * 16 * 40);
#pragma unroll
      for (int nb = 0; nb < 4; ++nb)
        acc[mb][nb] = __builtin_amdgcn_mfma_f32_16x16x32_bf16(af, bf[nb], acc[mb][nb], 0, 0, 0);
    }
  }

#pragma unroll
  for (int mb = 0; mb < 2; ++mb) {
    const int row0 = rowbase + wm * 32 + mb * 16 + l16 * 4;
#pragma unroll
    for (int r = 0; r < 4; ++r) {
      const int row = row0 + r;
      if (row < Nk) {
        float* zp = Z + ((size_t)kk * 2040 + row) * 256 + colbase + wn * 64 + l15;
#pragma unroll
        for (int nb = 0; nb < 4; ++nb) zp[nb * 16] = acc[mb][nb][r];
      }
    }
  }
}

// ---------- loss: wave per row; 4-lane groups, 64 channels of z per lane ----------
#define DOT64(PTR, OUT) do {                                                 \
    float d0_ = 0.f, d1_ = 0.f;                                              \
    _Pragma("unroll")                                                        \
    for (int c_ = 0; c_ < 8; ++c_) {                                         \
      const uint4 pv_ = *(const uint4*)((PTR) + c_ * 8);                     \
      const uint uu_[4] = {pv_.x, pv_.y, pv_.z, pv_.w};                      \
      _Pragma("unroll")                                                      \
      for (int q_ = 0; q_ < 4; ++q_) {                                       \
        const float f0_ = __uint_as_float(uu_[q_] << 16);                    \
        const float f1_ = __uint_as_float(uu_[q_] & 0xffff0000u);            \
        d0_ = fmaf(z[c_ * 8 + q_ * 2], f0_, d0_);                            \
        d1_ = fmaf(z[c_ * 8 + q_ * 2 + 1], f1_, d1_);                        \
      }                                                                      \
    }                                                                        \
    OUT = d0_ + d1_;                                                         \
  } while (0)

__global__ __launch_bounds__(256) void loss_kernel(
    const float* __restrict__ Z, const ushort* __restrict__ poolb,
    const int* __restrict__ neg_idx, float* __restrict__ acc) {
  const int kk = blockIdx.y;
  const int Tk = 255 - kk, Nk = 8 * Tk;
  const int tid = threadIdx.x;
  const int wid = tid >> 6, lane = tid & 63;
  const int n = blockIdx.x * 4 + wid;
  const int cg = lane & 3;   // 64-channel chunk index
  const int g = lane >> 2;   // neg group 0..15 (8 negs each)
  float wave_loss = 0.f;
  if (n < Nk) {
    const float* zr = Z + ((size_t)kk * 2040 + n) * 256 + cg * 64;
    float z[64];
#pragma unroll
    for (int i = 0; i < 16; ++i) {
      const float4 v = *(const float4*)(zr + i * 4);
      z[i * 4] = v.x; z[i * 4 + 1] = v.y; z[i * 4 + 2] = v.z; z[i * 4 + 3] = v.w;
    }
    float ss = 0.f;
#pragma unroll
    for (int i = 0; i < 64; ++i) ss = fmaf(z[i], z[i], ss);
    ss += __shfl_xor(ss, 1);
    ss += __shfl_xor(ss, 2);
    const float sc = rsqrtf(ss) * INV_TEMP;  // logit = dot * sc

    const int bb = n / Tk, tt = n - bb * Tk;
    const ushort* pp = poolb + (size_t)(bb * 256 + tt + kk + 1) * 256 + cg * 64;
    float pd;
    DOT64(pp, pd);
    pd += __shfl_xor(pd, 1);
    pd += __shfl_xor(pd, 2);
    const float pos = pd * sc;

    const int* ip = neg_idx + ((size_t)kk * 2040 + n) * 128 + g * 8;
    const int4 ia = *(const int4*)ip;
    const int4 ib = *(const int4*)(ip + 4);
    const int idxs[8] = {ia.x, ia.y, ia.z, ia.w, ib.x, ib.y, ib.z, ib.w};
    float ssum = 0.f;
#pragma unroll
    for (int i = 0; i < 8; ++i) {
      const ushort* pr = poolb + (size_t)idxs[i] * 256 + cg * 64;
      float d;
      DOT64(pr, d);
      d += __shfl_xor(d, 1);
      d += __shfl_xor(d, 2);
      ssum += __expf(fmaf(d, sc, -LOGIT_MAX));
    }
    ssum += __shfl_xor(ssum, 4);
    ssum += __shfl_xor(ssum, 8);
    ssum += __shfl_xor(ssum, 16);
    ssum += __shfl_xor(ssum, 32);
    ssum += __expf(pos - LOGIT_MAX);
    wave_loss = LOGIT_MAX + __logf(ssum) - pos;
  }
  __shared__ float bl[4];
  if (lane == 0) bl[wid] = wave_loss;
  __syncthreads();
  if (tid == 0) atomicAdd(&acc[kk], bl[0] + bl[1] + bl[2] + bl[3]);
}

__global__ void finalize_kernel(const float* __restrict__ acc,
                                float* __restrict__ out) {
  if (threadIdx.x == 0) {
    float tot = 0.f;
#pragma unroll
    for (int kk = 0; kk < 12; ++kk) tot += acc[kk] / (8.0f * (255 - kk));
    out[0] = tot / 12.0f;
  }
}

extern "C" void kernel_launch(void* const* d_in, const int* in_sizes, int n_in,
                              void* d_out, int out_size, void* d_ws, size_t ws_size,
                              hipStream_t stream) {
  const float* ctx = (const float*)d_in[0];   // (8,256,512)
  const float* enc = (const float*)d_in[1];   // (8,256,256)
  const float* W   = (const float*)d_in[2];   // (12,256,512)
  const int*   neg = (const int*)d_in[3];     // (12,2040,128)
  float* out = (float*)d_out;

  char* ws = (char*)d_ws;
  ushort* poolb = (ushort*)(ws);                        // 2048*256*2 = 1,048,576 B
  float* Z      = (float*)(ws + 1048576);               // 12*2040*256*4 = 25,067,520 B
  float* acc    = (float*)(ws + 1048576 + 25067520);    // 12 floats

  hipMemsetAsync(acc, 0, 12 * sizeof(float), stream);
  pool_norm_kernel<<<dim3(128), dim3(256), 0, stream>>>(enc, poolb);
  zhat_gemm_kernel<<<dim3(2, 32, 12), dim3(256), 0, stream>>>(ctx, W, Z);
  loss_kernel<<<dim3(510, 12), dim3(256), 0, stream>>>(Z, poolb, neg, acc);
  finalize_kernel<<<dim3(1), dim3(64), 0, stream>>>(acc, out);
}

// Round 3
// 127.732 us; speedup vs baseline: 2.3159x; 2.3159x over previous
//
#include <hip/hip_runtime.h>
#include <hip/hip_bf16.h>

typedef __attribute__((ext_vector_type(8))) short short8;
typedef __attribute__((ext_vector_type(4))) float f32x4;

#define INV_TEMP 14.285714285714286f
#define LOGIT_MAX 14.2857143f

__device__ __forceinline__ float dot4f(const float4 a, const float4 b) {
  return a.x * b.x + a.y * b.y + a.z * b.z + a.w * b.w;
}

__device__ __forceinline__ ushort bf16c(float f) {
  uint u = __float_as_uint(f);
  uint r = (u + 0x7fffu + ((u >> 16) & 1u)) >> 16;
  return (ushort)r;
}

__device__ __forceinline__ uint pk2(float a, float b) {
  return (uint)bf16c(a) | ((uint)bf16c(b) << 16);
}

// DPP-based 16-lane tree sum: quad_perm xor1, quad_perm xor2,
// row_half_mirror (combines quads), row_mirror (combines 8-halves).
template <int CTRL>
__device__ __forceinline__ float dpp_add(float v) {
  const int x = __builtin_amdgcn_mov_dpp(__float_as_int(v), CTRL, 0xF, 0xF, true);
  return v + __int_as_float(x);
}
__device__ __forceinline__ float qsum16(float v) {
  v = dpp_add<0xB1>(v);   // quad_perm [1,0,3,2]
  v = dpp_add<0x4E>(v);   // quad_perm [2,3,0,1]
  v = dpp_add<0x141>(v);  // row_half_mirror
  v = dpp_add<0x140>(v);  // row_mirror
  return v;
}

// ---------- pool = l2norm(encoded.reshape(2048,256)) -> bf16 ----------
__global__ __launch_bounds__(256) void pool_norm_kernel(
    const float* __restrict__ enc, ushort* __restrict__ poolb) {
  const int tid = threadIdx.x;
  const int grp = tid >> 4, lane = tid & 15;
  const int r = blockIdx.x * 16 + grp;  // 0..2047
  const float* src = enc + (size_t)r * 256;
  float4 v0 = *(const float4*)(src + lane * 4);
  float4 v1 = *(const float4*)(src + 64 + lane * 4);
  float4 v2 = *(const float4*)(src + 128 + lane * 4);
  float4 v3 = *(const float4*)(src + 192 + lane * 4);
  float ss = dot4f(v0, v0) + dot4f(v1, v1) + dot4f(v2, v2) + dot4f(v3, v3);
  ss = qsum16(ss);
  const float inv = rsqrtf(ss);
  ushort* dst = poolb + (size_t)r * 256;
  ushort4 o;
  o = make_ushort4(bf16c(v0.x * inv), bf16c(v0.y * inv), bf16c(v0.z * inv), bf16c(v0.w * inv));
  *(ushort4*)(dst + lane * 4) = o;
  o = make_ushort4(bf16c(v1.x * inv), bf16c(v1.y * inv), bf16c(v1.z * inv), bf16c(v1.w * inv));
  *(ushort4*)(dst + 64 + lane * 4) = o;
  o = make_ushort4(bf16c(v2.x * inv), bf16c(v2.y * inv), bf16c(v2.z * inv), bf16c(v2.w * inv));
  *(ushort4*)(dst + 128 + lane * 4) = o;
  o = make_ushort4(bf16c(v3.x * inv), bf16c(v3.y * inv), bf16c(v3.z * inv), bf16c(v3.w * inv));
  *(ushort4*)(dst + 192 + lane * 4) = o;
}

// ---------- z_hat[k] = ctx_rows @ W[k]^T via bf16 MFMA, fp32 out ----------
// Tile: BM=64, BN=128, BK=32. 256 threads = 4 waves (2x2), wave tile 32x64.
__global__ __launch_bounds__(256) void zhat_gemm_kernel(
    const float* __restrict__ ctx, const float* __restrict__ W,
    float* __restrict__ Z) {
  const int kk = blockIdx.z;
  const int Tk = 255 - kk, Nk = 8 * Tk;
  const int rowbase = blockIdx.y * 64;
  if (rowbase >= Nk) return;
  const int colbase = blockIdx.x * 128;

  __shared__ ushort As[64 * 40];   // row stride 40 bf16 (pad 8)
  __shared__ ushort Bs[128 * 40];

  const int tid = threadIdx.x;
  const int arow = tid & 63;
  const int akseg = (tid >> 6) * 8;
  int n = rowbase + arow;
  if (n >= Nk) n = Nk - 1;  // clamp (valid memory; result rows discarded)
  const int bb = n / Tk, tt = n - bb * Tk;
  const float* aptr = ctx + ((size_t)(bb * 256 + tt)) * 512 + akseg;
  const int brow = tid & 127;
  const int bkseg = (tid >> 7) * 16;
  const float* bptr = W + ((size_t)kk * 256 + colbase + brow) * 512 + bkseg;

  const int wid = tid >> 6, lane = tid & 63;
  const int wm = wid >> 1, wn = wid & 1;
  const int l15 = lane & 15, l16 = lane >> 4;

  f32x4 acc[2][4];
#pragma unroll
  for (int i = 0; i < 2; ++i)
#pragma unroll
    for (int j = 0; j < 4; ++j) acc[i][j] = (f32x4){0.f, 0.f, 0.f, 0.f};

  const ushort* aread = &As[(wm * 32 + l15) * 40 + l16 * 8];
  const ushort* bread = &Bs[(wn * 64 + l15) * 40 + l16 * 8];

  for (int k0 = 0; k0 < 512; k0 += 32) {
    const float4 a0 = *(const float4*)(aptr + k0);
    const float4 a1 = *(const float4*)(aptr + k0 + 4);
    const float4 b0 = *(const float4*)(bptr + k0);
    const float4 b1 = *(const float4*)(bptr + k0 + 4);
    const float4 b2 = *(const float4*)(bptr + k0 + 8);
    const float4 b3 = *(const float4*)(bptr + k0 + 12);
    __syncthreads();
    {
      uint4 w0 = make_uint4(pk2(a0.x, a0.y), pk2(a0.z, a0.w), pk2(a1.x, a1.y), pk2(a1.z, a1.w));
      *(uint4*)&As[arow * 40 + akseg] = w0;
      uint4 w1 = make_uint4(pk2(b0.x, b0.y), pk2(b0.z, b0.w), pk2(b1.x, b1.y), pk2(b1.z, b1.w));
      *(uint4*)&Bs[brow * 40 + bkseg] = w1;
      uint4 w2 = make_uint4(pk2(b2.x, b2.y), pk2(b2.z, b2.w), pk2(b3.x, b3.y), pk2(b3.z, b3.w));
      *(uint4*)&Bs[brow * 40 + bkseg + 8] = w2;
    }
    __syncthreads();
    short8 bf[4];
#pragma unroll
    for (int nb = 0; nb < 4; ++nb) bf[nb] = *(const short8*)(bread + nb * 16 * 40);
#pragma unroll
    for (int mb = 0; mb < 2; ++mb) {
      short8 af = *(const short8*)(aread + mb * 16 * 40);
#pragma unroll
      for (int nb = 0; nb < 4; ++nb)
        acc[mb][nb] = __builtin_amdgcn_mfma_f32_16x16x32_bf16(af, bf[nb], acc[mb][nb], 0, 0, 0);
    }
  }

#pragma unroll
  for (int mb = 0; mb < 2; ++mb) {
    const int row0 = rowbase + wm * 32 + mb * 16 + l16 * 4;
#pragma unroll
    for (int r = 0; r < 4; ++r) {
      const int row = row0 + r;
      if (row < Nk) {
        float* zp = Z + ((size_t)kk * 2040 + row) * 256 + colbase + wn * 64 + l15;
#pragma unroll
        for (int nb = 0; nb < 4; ++nb) zp[nb * 16] = acc[mb][nb][r];
      }
    }
  }
}

// ---------- loss: 16 lanes per row, lane owns 16 channels (8 + 8), bf16 pool ----------
// dot of lane's 16 z channels with the matching bf16 pool chunk.
__device__ __forceinline__ float dot16(const uint4 p0, const uint4 p1,
                                       const float* __restrict__ z) {
  float d0 = 0.f, d1 = 0.f;
  const uint u[8] = {p0.x, p0.y, p0.z, p0.w, p1.x, p1.y, p1.z, p1.w};
#pragma unroll
  for (int q = 0; q < 8; ++q) {
    d0 = fmaf(z[q * 2],     __uint_as_float(u[q] << 16),         d0);
    d1 = fmaf(z[q * 2 + 1], __uint_as_float(u[q] & 0xffff0000u), d1);
  }
  return d0 + d1;
}

__global__ __launch_bounds__(256) void loss_kernel(
    const float* __restrict__ Z, const ushort* __restrict__ poolb,
    const int* __restrict__ neg_idx, float* __restrict__ acc) {
  const int kk = blockIdx.y;
  const int Tk = 255 - kk, Nk = 8 * Tk;
  const int tid = threadIdx.x;
  const int grp = tid >> 4, lane = tid & 15;
  const int n = blockIdx.x * 16 + grp;
  float row_loss = 0.f;
  if (n < Nk) {
    // lane's channels: [lane*8 .. lane*8+7] and [128+lane*8 .. +7]
    const float* zr = Z + ((size_t)kk * 2040 + n) * 256 + lane * 8;
    float z[16];
    {
      const float4 a = *(const float4*)(zr);
      const float4 b = *(const float4*)(zr + 4);
      const float4 c = *(const float4*)(zr + 128);
      const float4 d = *(const float4*)(zr + 132);
      z[0] = a.x; z[1] = a.y; z[2] = a.z; z[3] = a.w;
      z[4] = b.x; z[5] = b.y; z[6] = b.z; z[7] = b.w;
      z[8] = c.x; z[9] = c.y; z[10] = c.z; z[11] = c.w;
      z[12] = d.x; z[13] = d.y; z[14] = d.z; z[15] = d.w;
    }
    float ss = 0.f;
#pragma unroll
    for (int i = 0; i < 16; ++i) ss = fmaf(z[i], z[i], ss);
    ss = qsum16(ss);
    const float sc = rsqrtf(ss) * INV_TEMP;  // logit = dot * sc

    const int bb = n / Tk, tt = n - bb * Tk;
    const ushort* pp = poolb + (size_t)(bb * 256 + tt + kk + 1) * 256 + lane * 8;
    float pd = qsum16(dot16(*(const uint4*)pp, *(const uint4*)(pp + 128), z));
    const float pos = pd * sc;

    const int* ip = neg_idx + ((size_t)kk * 2040 + n) * 128;
    float ssum = __expf(pos - LOGIT_MAX);
#pragma unroll 2
    for (int j4 = 0; j4 < 32; ++j4) {
      const int4 iv = *(const int4*)(ip + j4 * 4);
      const int idxs[4] = {iv.x, iv.y, iv.z, iv.w};
#pragma unroll
      for (int i = 0; i < 4; ++i) {
        const ushort* pr = poolb + (size_t)idxs[i] * 256 + lane * 8;
        const uint4 p0 = *(const uint4*)pr;
        const uint4 p1 = *(const uint4*)(pr + 128);
        const float d = qsum16(dot16(p0, p1, z));
        ssum += __expf(fmaf(d, sc, -LOGIT_MAX));
      }
    }
    row_loss = LOGIT_MAX + __logf(ssum) - pos;
  }
  __shared__ float bl[16];
  if (lane == 0) bl[grp] = row_loss;
  __syncthreads();
  if (tid == 0) {
    float s = 0.f;
#pragma unroll
    for (int i = 0; i < 16; ++i) s += bl[i];
    atomicAdd(&acc[kk], s);
  }
}

__global__ void finalize_kernel(const float* __restrict__ acc,
                                float* __restrict__ out) {
  if (threadIdx.x == 0) {
    float tot = 0.f;
#pragma unroll
    for (int kk = 0; kk < 12; ++kk) tot += acc[kk] / (8.0f * (255 - kk));
    out[0] = tot / 12.0f;
  }
}

extern "C" void kernel_launch(void* const* d_in, const int* in_sizes, int n_in,
                              void* d_out, int out_size, void* d_ws, size_t ws_size,
                              hipStream_t stream) {
  const float* ctx = (const float*)d_in[0];   // (8,256,512)
  const float* enc = (const float*)d_in[1];   // (8,256,256)
  const float* W   = (const float*)d_in[2];   // (12,256,512)
  const int*   neg = (const int*)d_in[3];     // (12,2040,128)
  float* out = (float*)d_out;

  char* ws = (char*)d_ws;
  ushort* poolb = (ushort*)(ws);                        // 2048*256*2 = 1,048,576 B
  float* Z      = (float*)(ws + 1048576);               // 12*2040*256*4 = 25,067,520 B
  float* acc    = (float*)(ws + 1048576 + 25067520);    // 12 floats

  hipMemsetAsync(acc, 0, 12 * sizeof(float), stream);
  pool_norm_kernel<<<dim3(128), dim3(256), 0, stream>>>(enc, poolb);
  zhat_gemm_kernel<<<dim3(2, 32, 12), dim3(256), 0, stream>>>(ctx, W, Z);
  loss_kernel<<<dim3(128, 12), dim3(256), 0, stream>>>(Z, poolb, neg, acc);
  finalize_kernel<<<dim3(1), dim3(64), 0, stream>>>(acc, out);
}

// Round 4
// 110.470 us; speedup vs baseline: 2.6778x; 1.1563x over previous
//
#include <hip/hip_runtime.h>
#include <hip/hip_bf16.h>

typedef __attribute__((ext_vector_type(8))) short short8;
typedef __attribute__((ext_vector_type(4))) float f32x4;
typedef _Float16 __attribute__((ext_vector_type(2))) half2v;

#define INV_TEMP 14.285714285714286f
#define LOGIT_MAX 14.2857143f

__device__ __forceinline__ float dot4f(const float4 a, const float4 b) {
  return a.x * b.x + a.y * b.y + a.z * b.z + a.w * b.w;
}

__device__ __forceinline__ ushort bf16c(float f) {
  uint u = __float_as_uint(f);
  uint r = (u + 0x7fffu + ((u >> 16) & 1u)) >> 16;
  return (ushort)r;
}
__device__ __forceinline__ uint pk2(float a, float b) {
  return (uint)bf16c(a) | ((uint)bf16c(b) << 16);
}
// f32 pair -> packed f16 (RTZ), as uint
__device__ __forceinline__ uint pkh(float a, float b) {
  return __builtin_bit_cast(uint, __builtin_amdgcn_cvt_pkrtz(a, b));
}
__device__ __forceinline__ half2v h2(uint u) {
  return __builtin_bit_cast(half2v, u);
}
__device__ __forceinline__ float fdot2(half2v a, half2v b, float c) {
  return __builtin_amdgcn_fdot2(a, b, c, false);
}

// DPP-based 16-lane tree sum.
template <int CTRL>
__device__ __forceinline__ float dpp_add(float v) {
  const int x = __builtin_amdgcn_mov_dpp(__float_as_int(v), CTRL, 0xF, 0xF, true);
  return v + __int_as_float(x);
}
__device__ __forceinline__ float qsum16(float v) {
  v = dpp_add<0xB1>(v);   // quad_perm [1,0,3,2]
  v = dpp_add<0x4E>(v);   // quad_perm [2,3,0,1]
  v = dpp_add<0x141>(v);  // row_half_mirror
  v = dpp_add<0x140>(v);  // row_mirror
  return v;
}

// ---------- fp32 -> bf16 elementwise (8 per thread) ----------
__global__ __launch_bounds__(256) void cvt_bf16_kernel(
    const float* __restrict__ in, ushort* __restrict__ out) {
  const int i = blockIdx.x * 256 + threadIdx.x;
  const float4 a = *(const float4*)(in + (size_t)i * 8);
  const float4 b = *(const float4*)(in + (size_t)i * 8 + 4);
  const uint4 o = make_uint4(pk2(a.x, a.y), pk2(a.z, a.w), pk2(b.x, b.y), pk2(b.z, b.w));
  *(uint4*)(out + (size_t)i * 8) = o;
}

// ---------- pool = l2norm(encoded.reshape(2048,256)) -> f16 pairs (c, c+16) ----------
// uint u = blk*16 + j holds (row[blk*32+j], row[blk*32+j+16]); 128 uints/row.
__global__ __launch_bounds__(256) void pool_norm_kernel(
    const float* __restrict__ enc, uint* __restrict__ poolh) {
  const int tid = threadIdx.x;
  const int grp = tid >> 4, lane = tid & 15;
  const int r = blockIdx.x * 16 + grp;  // 0..2047
  const float* src = enc + (size_t)r * 256;
  const int blk2 = lane >> 2, j0 = (lane & 3) * 4;
  float4 a0 = *(const float4*)(src + blk2 * 32 + j0);
  float4 b0 = *(const float4*)(src + blk2 * 32 + j0 + 16);
  float4 a1 = *(const float4*)(src + 128 + blk2 * 32 + j0);
  float4 b1 = *(const float4*)(src + 128 + blk2 * 32 + j0 + 16);
  float ss = dot4f(a0, a0) + dot4f(b0, b0) + dot4f(a1, a1) + dot4f(b1, b1);
  ss = qsum16(ss);
  const float inv = rsqrtf(ss);
  uint* dst = poolh + (size_t)r * 128;
  uint4 o;
  o = make_uint4(pkh(a0.x * inv, b0.x * inv), pkh(a0.y * inv, b0.y * inv),
                 pkh(a0.z * inv, b0.z * inv), pkh(a0.w * inv, b0.w * inv));
  *(uint4*)(dst + blk2 * 16 + j0) = o;
  o = make_uint4(pkh(a1.x * inv, b1.x * inv), pkh(a1.y * inv, b1.y * inv),
                 pkh(a1.z * inv, b1.z * inv), pkh(a1.w * inv, b1.w * inv));
  *(uint4*)(dst + 64 + blk2 * 16 + j0) = o;
}

// ---------- z_hat[k] = ctx_rows @ W[k]^T via bf16 MFMA, f16-pair out ----------
// Tile: BM=64, BN=128, BK=32. 256 threads = 4 waves (2x2), wave tile 32x64.
__global__ __launch_bounds__(256) void zhat_gemm_kernel(
    const ushort* __restrict__ ctxb, const ushort* __restrict__ Wb,
    uint* __restrict__ Zp) {
  const int kk = blockIdx.z;
  const int Tk = 255 - kk, Nk = 8 * Tk;
  const int rowbase = blockIdx.y * 64;
  if (rowbase >= Nk) return;
  const int colbase = blockIdx.x * 128;

  __shared__ ushort As[64 * 40];   // row stride 40 bf16 (80 B, 16B-aligned)
  __shared__ ushort Bs[128 * 40];

  const int tid = threadIdx.x;
  const int arow = tid & 63;
  const int akseg = (tid >> 6) * 8;       // {0,8,16,24}
  int n = rowbase + arow;
  if (n >= Nk) n = Nk - 1;  // clamp (valid memory; result rows discarded)
  const int bb = n / Tk, tt = n - bb * Tk;
  const ushort* aptr = ctxb + ((size_t)(bb * 256 + tt)) * 512 + akseg;
  const int brow = tid & 127;
  const int bk0 = (tid >> 7) * 8;         // {0,8}
  const ushort* bptr = Wb + ((size_t)kk * 256 + colbase + brow) * 512 + bk0;

  const int wid = tid >> 6, lane = tid & 63;
  const int wm = wid >> 1, wn = wid & 1;
  const int l15 = lane & 15, l16 = lane >> 4;

  f32x4 acc[2][4];
#pragma unroll
  for (int i = 0; i < 2; ++i)
#pragma unroll
    for (int j = 0; j < 4; ++j) acc[i][j] = (f32x4){0.f, 0.f, 0.f, 0.f};

  const ushort* aread = &As[(wm * 32 + l15) * 40 + l16 * 8];
  const ushort* bread = &Bs[(wn * 64 + l15) * 40 + l16 * 8];

  for (int k0 = 0; k0 < 512; k0 += 32) {
    const uint4 av = *(const uint4*)(aptr + k0);
    const uint4 bv0 = *(const uint4*)(bptr + k0);
    const uint4 bv1 = *(const uint4*)(bptr + k0 + 16);
    __syncthreads();
    *(uint4*)&As[arow * 40 + akseg] = av;
    *(uint4*)&Bs[brow * 40 + bk0] = bv0;
    *(uint4*)&Bs[brow * 40 + bk0 + 16] = bv1;
    __syncthreads();
    short8 bf[4];
#pragma unroll
    for (int nb = 0; nb < 4; ++nb) bf[nb] = *(const short8*)(bread + nb * 16 * 40);
#pragma unroll
    for (int mb = 0; mb < 2; ++mb) {
      short8 af = *(const short8*)(aread + mb * 16 * 40);
#pragma unroll
      for (int nb = 0; nb < 4; ++nb)
        acc[mb][nb] = __builtin_amdgcn_mfma_f32_16x16x32_bf16(af, bf[nb], acc[mb][nb], 0, 0, 0);
    }
  }

  // Epilogue: pack (col c, col c+16) pairs lane-locally -> uint, 128 uints/row.
#pragma unroll
  for (int mb = 0; mb < 2; ++mb) {
    const int row0 = rowbase + wm * 32 + mb * 16 + l16 * 4;
#pragma unroll
    for (int r = 0; r < 4; ++r) {
      const int row = row0 + r;
      if (row < Nk) {
        uint* zp = Zp + ((size_t)kk * 2040 + row) * 128 + wn * 32 + l15;
        zp[0]  = pkh(acc[mb][0][r], acc[mb][1][r]);
        zp[16] = pkh(acc[mb][2][r], acc[mb][3][r]);
      }
    }
  }
}

// ---------- loss: 16 lanes/row; lane owns 8 consecutive uints (16 chans) ----------
__device__ __forceinline__ float dot8h(const half2v* __restrict__ zh,
                                       const uint4 p0, const uint4 p1) {
  float d = fdot2(zh[0], h2(p0.x), 0.f);
  d = fdot2(zh[1], h2(p0.y), d);
  d = fdot2(zh[2], h2(p0.z), d);
  d = fdot2(zh[3], h2(p0.w), d);
  d = fdot2(zh[4], h2(p1.x), d);
  d = fdot2(zh[5], h2(p1.y), d);
  d = fdot2(zh[6], h2(p1.z), d);
  d = fdot2(zh[7], h2(p1.w), d);
  return d;
}

__global__ __launch_bounds__(256) void loss_kernel(
    const uint* __restrict__ Zp, const uint* __restrict__ poolh,
    const int* __restrict__ neg_idx, float* __restrict__ acc) {
  const int kk = blockIdx.y;
  const int Tk = 255 - kk, Nk = 8 * Tk;
  const int tid = threadIdx.x;
  const int grp = tid >> 4, lane = tid & 15;
  const int n = blockIdx.x * 16 + grp;
  float row_loss = 0.f;
  if (n < Nk) {
    const uint* zr = Zp + ((size_t)kk * 2040 + n) * 128 + lane * 8;
    const uint4 za = *(const uint4*)zr;
    const uint4 zb = *(const uint4*)(zr + 4);
    half2v zh[8] = {h2(za.x), h2(za.y), h2(za.z), h2(za.w),
                    h2(zb.x), h2(zb.y), h2(zb.z), h2(zb.w)};
    float ss = 0.f;
#pragma unroll
    for (int q = 0; q < 8; ++q) ss = fdot2(zh[q], zh[q], ss);
    ss = qsum16(ss);
    const float sc = rsqrtf(ss) * INV_TEMP;  // logit = dot * sc

    const int bb = n / Tk, tt = n - bb * Tk;
    const uint* pp = poolh + (size_t)(bb * 256 + tt + kk + 1) * 128 + lane * 8;
    float pd = qsum16(dot8h(zh, *(const uint4*)pp, *(const uint4*)(pp + 4)));
    const float pos = pd * sc;

    const int* ip = neg_idx + ((size_t)kk * 2040 + n) * 128;
    float ssum = __expf(pos - LOGIT_MAX);
#pragma unroll 2
    for (int j4 = 0; j4 < 32; ++j4) {
      const int4 iv = *(const int4*)(ip + j4 * 4);
      const int idxs[4] = {iv.x, iv.y, iv.z, iv.w};
#pragma unroll
      for (int i = 0; i < 4; ++i) {
        const uint* pr = poolh + ((size_t)idxs[i]) * 128 + lane * 8;
        const uint4 p0 = *(const uint4*)pr;
        const uint4 p1 = *(const uint4*)(pr + 4);
        const float d = qsum16(dot8h(zh, p0, p1));
        ssum += __expf(fmaf(d, sc, -LOGIT_MAX));
      }
    }
    row_loss = LOGIT_MAX + __logf(ssum) - pos;
  }
  __shared__ float bl[16];
  if (lane == 0) bl[grp] = row_loss;
  __syncthreads();
  if (tid == 0) {
    float s = 0.f;
#pragma unroll
    for (int i = 0; i < 16; ++i) s += bl[i];
    atomicAdd(&acc[kk], s);
  }
}

__global__ void finalize_kernel(const float* __restrict__ acc,
                                float* __restrict__ out) {
  if (threadIdx.x == 0) {
    float tot = 0.f;
#pragma unroll
    for (int kk = 0; kk < 12; ++kk) tot += acc[kk] / (8.0f * (255 - kk));
    out[0] = tot / 12.0f;
  }
}

extern "C" void kernel_launch(void* const* d_in, const int* in_sizes, int n_in,
                              void* d_out, int out_size, void* d_ws, size_t ws_size,
                              hipStream_t stream) {
  const float* ctx = (const float*)d_in[0];   // (8,256,512)
  const float* enc = (const float*)d_in[1];   // (8,256,256)
  const float* W   = (const float*)d_in[2];   // (12,256,512)
  const int*   neg = (const int*)d_in[3];     // (12,2040,128)
  float* out = (float*)d_out;

  char* ws = (char*)d_ws;
  uint*   poolh = (uint*)(ws);                      // 2048*128*4  = 1,048,576 B
  ushort* ctxb  = (ushort*)(ws + 1048576);          // 1,048,576*2 = 2,097,152 B
  ushort* Wb    = (ushort*)(ws + 3145728);          // 1,572,864*2 = 3,145,728 B
  uint*   Zp    = (uint*)(ws + 6291456);            // 12*2040*128*4 = 12,533,760 B
  float*  acc   = (float*)(ws + 6291456 + 12533760);

  hipMemsetAsync(acc, 0, 12 * sizeof(float), stream);
  cvt_bf16_kernel<<<dim3(512), dim3(256), 0, stream>>>(ctx, ctxb);
  cvt_bf16_kernel<<<dim3(768), dim3(256), 0, stream>>>(W, Wb);
  pool_norm_kernel<<<dim3(128), dim3(256), 0, stream>>>(enc, poolh);
  zhat_gemm_kernel<<<dim3(2, 32, 12), dim3(256), 0, stream>>>(ctxb, Wb, Zp);
  loss_kernel<<<dim3(128, 12), dim3(256), 0, stream>>>(Zp, poolh, neg, acc);
  finalize_kernel<<<dim3(1), dim3(64), 0, stream>>>(acc, out);
}

// Round 5
// 102.027 us; speedup vs baseline: 2.8994x; 1.0828x over previous
//
#include <hip/hip_runtime.h>
#include <hip/hip_bf16.h>

typedef __attribute__((ext_vector_type(8))) short short8;
typedef __attribute__((ext_vector_type(4))) float f32x4;
typedef _Float16 __attribute__((ext_vector_type(2))) half2v;

#define INV_TEMP 14.285714285714286f
#define LOGIT_MAX 14.2857143f
#define L2E 1.44269504f
#define OFFE (LOGIT_MAX * L2E)

__device__ __forceinline__ float dot4f(const float4 a, const float4 b) {
  return a.x * b.x + a.y * b.y + a.z * b.z + a.w * b.w;
}

__device__ __forceinline__ ushort bf16c(float f) {
  uint u = __float_as_uint(f);
  uint r = (u + 0x7fffu + ((u >> 16) & 1u)) >> 16;
  return (ushort)r;
}
__device__ __forceinline__ uint pk2(float a, float b) {
  return (uint)bf16c(a) | ((uint)bf16c(b) << 16);
}
// f32 pair -> packed f16 (RTZ), as uint
__device__ __forceinline__ uint pkh(float a, float b) {
  return __builtin_bit_cast(uint, __builtin_amdgcn_cvt_pkrtz(a, b));
}
__device__ __forceinline__ half2v h2(uint u) {
  return __builtin_bit_cast(half2v, u);
}
__device__ __forceinline__ float fdot2(half2v a, half2v b, float c) {
  return __builtin_amdgcn_fdot2(a, b, c, false);
}

// DPP-based 16-lane tree sum.
template <int CTRL>
__device__ __forceinline__ float dpp_add(float v) {
  const int x = __builtin_amdgcn_mov_dpp(__float_as_int(v), CTRL, 0xF, 0xF, true);
  return v + __int_as_float(x);
}
__device__ __forceinline__ float qsum16(float v) {
  v = dpp_add<0xB1>(v);   // quad_perm [1,0,3,2]
  v = dpp_add<0x4E>(v);   // quad_perm [2,3,0,1]
  v = dpp_add<0x141>(v);  // row_half_mirror
  v = dpp_add<0x140>(v);  // row_mirror
  return v;
}

// Two 4-deep fdot2 chains (shorter serial latency than one 8-chain).
__device__ __forceinline__ float dot8h2(const half2v* __restrict__ zh,
                                        const uint4 p0, const uint4 p1) {
  float d0 = fdot2(zh[0], h2(p0.x), 0.f);
  float d1 = fdot2(zh[1], h2(p0.y), 0.f);
  d0 = fdot2(zh[2], h2(p0.z), d0);
  d1 = fdot2(zh[3], h2(p0.w), d1);
  d0 = fdot2(zh[4], h2(p1.x), d0);
  d1 = fdot2(zh[5], h2(p1.y), d1);
  d0 = fdot2(zh[6], h2(p1.z), d0);
  d1 = fdot2(zh[7], h2(p1.w), d1);
  return d0 + d1;
}

// ---------- fp32 -> bf16 elementwise (8 per thread) ----------
__global__ __launch_bounds__(256) void cvt_bf16_kernel(
    const float* __restrict__ in, ushort* __restrict__ out) {
  const int i = blockIdx.x * 256 + threadIdx.x;
  const float4 a = *(const float4*)(in + (size_t)i * 8);
  const float4 b = *(const float4*)(in + (size_t)i * 8 + 4);
  const uint4 o = make_uint4(pk2(a.x, a.y), pk2(a.z, a.w), pk2(b.x, b.y), pk2(b.z, b.w));
  *(uint4*)(out + (size_t)i * 8) = o;
}

// ---------- pool = l2norm(encoded.reshape(2048,256)) -> f16 pairs ----------
// uint u holds chans (c, c+16) with c = 2*(u & ~15) + (u & 15)  [matches Zp].
__global__ __launch_bounds__(256) void pool_norm_kernel(
    const float* __restrict__ enc, uint* __restrict__ poolh) {
  const int tid = threadIdx.x;
  const int grp = tid >> 4, lane = tid & 15;
  const int r = blockIdx.x * 16 + grp;  // 0..2047
  const float* src = enc + (size_t)r * 256;
  const int blk2 = lane >> 2, j0 = (lane & 3) * 4;
  float4 a0 = *(const float4*)(src + blk2 * 32 + j0);
  float4 b0 = *(const float4*)(src + blk2 * 32 + j0 + 16);
  float4 a1 = *(const float4*)(src + 128 + blk2 * 32 + j0);
  float4 b1 = *(const float4*)(src + 128 + blk2 * 32 + j0 + 16);
  float ss = dot4f(a0, a0) + dot4f(b0, b0) + dot4f(a1, a1) + dot4f(b1, b1);
  ss = qsum16(ss);
  const float inv = rsqrtf(ss);
  uint* dst = poolh + (size_t)r * 128;
  uint4 o;
  o = make_uint4(pkh(a0.x * inv, b0.x * inv), pkh(a0.y * inv, b0.y * inv),
                 pkh(a0.z * inv, b0.z * inv), pkh(a0.w * inv, b0.w * inv));
  *(uint4*)(dst + blk2 * 16 + j0) = o;
  o = make_uint4(pkh(a1.x * inv, b1.x * inv), pkh(a1.y * inv, b1.y * inv),
                 pkh(a1.z * inv, b1.z * inv), pkh(a1.w * inv, b1.w * inv));
  *(uint4*)(dst + 64 + blk2 * 16 + j0) = o;
}

// ---------- z_hat[k] = ctx_rows @ W[k]^T via bf16 MFMA, f16-pair out ----------
__global__ __launch_bounds__(256) void zhat_gemm_kernel(
    const ushort* __restrict__ ctxb, const ushort* __restrict__ Wb,
    uint* __restrict__ Zp) {
  const int kk = blockIdx.z;
  const int Tk = 255 - kk, Nk = 8 * Tk;
  const int rowbase = blockIdx.y * 64;
  if (rowbase >= Nk) return;
  const int colbase = blockIdx.x * 128;

  __shared__ ushort As[64 * 40];   // row stride 40 bf16 (80 B, 16B-aligned)
  __shared__ ushort Bs[128 * 40];

  const int tid = threadIdx.x;
  const int arow = tid & 63;
  const int akseg = (tid >> 6) * 8;       // {0,8,16,24}
  int n = rowbase + arow;
  if (n >= Nk) n = Nk - 1;  // clamp (valid memory; result rows discarded)
  const int bb = n / Tk, tt = n - bb * Tk;
  const ushort* aptr = ctxb + ((size_t)(bb * 256 + tt)) * 512 + akseg;
  const int brow = tid & 127;
  const int bk0 = (tid >> 7) * 8;         // {0,8}
  const ushort* bptr = Wb + ((size_t)kk * 256 + colbase + brow) * 512 + bk0;

  const int wid = tid >> 6, lane = tid & 63;
  const int wm = wid >> 1, wn = wid & 1;
  const int l15 = lane & 15, l16 = lane >> 4;

  f32x4 acc[2][4];
#pragma unroll
  for (int i = 0; i < 2; ++i)
#pragma unroll
    for (int j = 0; j < 4; ++j) acc[i][j] = (f32x4){0.f, 0.f, 0.f, 0.f};

  const ushort* aread = &As[(wm * 32 + l15) * 40 + l16 * 8];
  const ushort* bread = &Bs[(wn * 64 + l15) * 40 + l16 * 8];

  for (int k0 = 0; k0 < 512; k0 += 32) {
    const uint4 av = *(const uint4*)(aptr + k0);
    const uint4 bv0 = *(const uint4*)(bptr + k0);
    const uint4 bv1 = *(const uint4*)(bptr + k0 + 16);
    __syncthreads();
    *(uint4*)&As[arow * 40 + akseg] = av;
    *(uint4*)&Bs[brow * 40 + bk0] = bv0;
    *(uint4*)&Bs[brow * 40 + bk0 + 16] = bv1;
    __syncthreads();
    short8 bf[4];
#pragma unroll
    for (int nb = 0; nb < 4; ++nb) bf[nb] = *(const short8*)(bread + nb * 16 * 40);
#pragma unroll
    for (int mb = 0; mb < 2; ++mb) {
      short8 af = *(const short8*)(aread + mb * 16 * 40);
#pragma unroll
      for (int nb = 0; nb < 4; ++nb)
        acc[mb][nb] = __builtin_amdgcn_mfma_f32_16x16x32_bf16(af, bf[nb], acc[mb][nb], 0, 0, 0);
    }
  }

  // Epilogue: pack (col c, col c+16) pairs lane-locally.
  // u = (colbase>>1) + wn*32 + {0,16} + l15  (FIX: colbase offset was missing)
#pragma unroll
  for (int mb = 0; mb < 2; ++mb) {
    const int row0 = rowbase + wm * 32 + mb * 16 + l16 * 4;
#pragma unroll
    for (int r = 0; r < 4; ++r) {
      const int row = row0 + r;
      if (row < Nk) {
        uint* zp = Zp + ((size_t)kk * 2040 + row) * 128 + (colbase >> 1) + wn * 32 + l15;
        zp[0]  = pkh(acc[mb][0][r], acc[mb][1][r]);
        zp[16] = pkh(acc[mb][2][r], acc[mb][3][r]);
      }
    }
  }
}

// ---------- loss: 16 lanes/row; double-buffered 4-neg register banks ----------
#define LD2(P0, P1, IDX)                                   \
  { const uint* p_ = pb + (size_t)(IDX) * 128;             \
    P0 = *(const uint4*)p_; P1 = *(const uint4*)(p_ + 4); }

#define ACC1(S, P0, P1)                                    \
  S += exp2f(fmaf(qsum16(dot8h2(zh, P0, P1)), sce, -OFFE));

__global__ __launch_bounds__(256) void loss_kernel(
    const uint* __restrict__ Zp, const uint* __restrict__ poolh,
    const int* __restrict__ neg_idx, float* __restrict__ acc) {
  const int kk = blockIdx.y;
  const int Tk = 255 - kk, Nk = 8 * Tk;
  const int tid = threadIdx.x;
  const int grp = tid >> 4, lane = tid & 15;
  const int n = blockIdx.x * 16 + grp;
  float row_loss = 0.f;
  if (n < Nk) {
    const uint* zr = Zp + ((size_t)kk * 2040 + n) * 128 + lane * 8;
    const uint4 za = *(const uint4*)zr;
    const uint4 zb = *(const uint4*)(zr + 4);
    half2v zh[8] = {h2(za.x), h2(za.y), h2(za.z), h2(za.w),
                    h2(zb.x), h2(zb.y), h2(zb.z), h2(zb.w)};
    float ss = 0.f;
#pragma unroll
    for (int q = 0; q < 8; ++q) ss = fdot2(zh[q], zh[q], ss);
    ss = qsum16(ss);
    const float sce = rsqrtf(ss) * (INV_TEMP * L2E);  // logit(base2) = dot * sce

    const uint* pb = poolh + lane * 8;
    const int bb = n / Tk, tt = n - bb * Tk;
    uint4 P0, P1;
    LD2(P0, P1, bb * 256 + tt + kk + 1);
    const float pose = qsum16(dot8h2(zh, P0, P1)) * sce;

    const int* ip = neg_idx + ((size_t)kk * 2040 + n) * 128;
    float s0 = 0.f, s1 = 0.f, s2 = 0.f, s3 = 0.f;
    uint4 A0, A1, B0, B1, C0, C1, D0, D1;
    uint4 E0, E1, F0, F1, G0, G1, H0, H1;
    {
      const int4 iv = *(const int4*)ip;
      LD2(A0, A1, iv.x) LD2(B0, B1, iv.y) LD2(C0, C1, iv.z) LD2(D0, D1, iv.w)
    }
    for (int j8 = 0; j8 < 16; ++j8) {
      {  // prefetch odd quad into bank E-H
        const int4 jv = *(const int4*)(ip + j8 * 8 + 4);
        LD2(E0, E1, jv.x) LD2(F0, F1, jv.y) LD2(G0, G1, jv.z) LD2(H0, H1, jv.w)
      }
      ACC1(s0, A0, A1) ACC1(s1, B0, B1) ACC1(s2, C0, C1) ACC1(s3, D0, D1)
      if (j8 < 15) {  // prefetch next even quad into bank A-D
        const int4 kv = *(const int4*)(ip + j8 * 8 + 8);
        LD2(A0, A1, kv.x) LD2(B0, B1, kv.y) LD2(C0, C1, kv.z) LD2(D0, D1, kv.w)
      }
      ACC1(s0, E0, E1) ACC1(s1, F0, F1) ACC1(s2, G0, G1) ACC1(s3, H0, H1)
    }
    const float ssum = (s0 + s1) + (s2 + s3) + exp2f(pose - OFFE);
    row_loss = LOGIT_MAX + 0.69314718f * (__log2f(ssum) - pose);
  }
  __shared__ float bl[16];
  if (lane == 0) bl[grp] = row_loss;
  __syncthreads();
  if (tid == 0) {
    float s = 0.f;
#pragma unroll
    for (int i = 0; i < 16; ++i) s += bl[i];
    atomicAdd(&acc[kk], s);
  }
}

__global__ void finalize_kernel(const float* __restrict__ acc,
                                float* __restrict__ out) {
  if (threadIdx.x == 0) {
    float tot = 0.f;
#pragma unroll
    for (int kk = 0; kk < 12; ++kk) tot += acc[kk] / (8.0f * (255 - kk));
    out[0] = tot / 12.0f;
  }
}

extern "C" void kernel_launch(void* const* d_in, const int* in_sizes, int n_in,
                              void* d_out, int out_size, void* d_ws, size_t ws_size,
                              hipStream_t stream) {
  const float* ctx = (const float*)d_in[0];   // (8,256,512)
  const float* enc = (const float*)d_in[1];   // (8,256,256)
  const float* W   = (const float*)d_in[2];   // (12,256,512)
  const int*   neg = (const int*)d_in[3];     // (12,2040,128)
  float* out = (float*)d_out;

  char* ws = (char*)d_ws;
  uint*   poolh = (uint*)(ws);                      // 2048*128*4  = 1,048,576 B
  ushort* ctxb  = (ushort*)(ws + 1048576);          // 2,097,152 B
  ushort* Wb    = (ushort*)(ws + 3145728);          // 3,145,728 B
  uint*   Zp    = (uint*)(ws + 6291456);            // 12*2040*128*4 = 12,533,760 B
  float*  acc   = (float*)(ws + 6291456 + 12533760);

  hipMemsetAsync(acc, 0, 12 * sizeof(float), stream);
  cvt_bf16_kernel<<<dim3(512), dim3(256), 0, stream>>>(ctx, ctxb);
  cvt_bf16_kernel<<<dim3(768), dim3(256), 0, stream>>>(W, Wb);
  pool_norm_kernel<<<dim3(128), dim3(256), 0, stream>>>(enc, poolh);
  zhat_gemm_kernel<<<dim3(2, 32, 12), dim3(256), 0, stream>>>(ctxb, Wb, Zp);
  loss_kernel<<<dim3(128, 12), dim3(256), 0, stream>>>(Zp, poolh, neg, acc);
  finalize_kernel<<<dim3(1), dim3(64), 0, stream>>>(acc, out);
}

// Round 6
// 95.662 us; speedup vs baseline: 3.0923x; 1.0665x over previous
//
#include <hip/hip_runtime.h>
#include <hip/hip_bf16.h>

typedef __attribute__((ext_vector_type(8))) short short8;
typedef __attribute__((ext_vector_type(4))) float f32x4;
typedef __attribute__((ext_vector_type(2))) float f32x2;
typedef _Float16 __attribute__((ext_vector_type(2))) half2v;

#define INV_TEMP 14.285714285714286f
#define LOGIT_MAX 14.2857143f
#define L2E 1.44269504f
#define OFFE (LOGIT_MAX * L2E)

__device__ __forceinline__ ushort bf16c(float f) {
  uint u = __float_as_uint(f);
  uint r = (u + 0x7fffu + ((u >> 16) & 1u)) >> 16;
  return (ushort)r;
}
__device__ __forceinline__ uint pk2(float a, float b) {
  return (uint)bf16c(a) | ((uint)bf16c(b) << 16);
}
// f32 pair -> packed f16 (RTZ), as uint
__device__ __forceinline__ uint pkh(float a, float b) {
  return __builtin_bit_cast(uint, __builtin_amdgcn_cvt_pkrtz(a, b));
}

// DPP-based 16-lane tree sum (compiler fuses mov_dpp+add -> v_add_f32_dpp).
template <int CTRL>
__device__ __forceinline__ float dpp_add(float v) {
  const int x = __builtin_amdgcn_mov_dpp(__float_as_int(v), CTRL, 0xF, 0xF, true);
  return v + __int_as_float(x);
}
__device__ __forceinline__ float qsum16(float v) {
  v = dpp_add<0xB1>(v);   // quad_perm [1,0,3,2]
  v = dpp_add<0x4E>(v);   // quad_perm [2,3,0,1]
  v = dpp_add<0x141>(v);  // row_half_mirror
  v = dpp_add<0x140>(v);  // row_mirror
  return v;
}

// ---------- fp32 -> bf16 elementwise (8 per thread) ----------
__global__ __launch_bounds__(256) void cvt_bf16_kernel(
    const float* __restrict__ in, ushort* __restrict__ out) {
  const int i = blockIdx.x * 256 + threadIdx.x;
  const float4 a = *(const float4*)(in + (size_t)i * 8);
  const float4 b = *(const float4*)(in + (size_t)i * 8 + 4);
  const uint4 o = make_uint4(pk2(a.x, a.y), pk2(a.z, a.w), pk2(b.x, b.y), pk2(b.z, b.w));
  *(uint4*)(out + (size_t)i * 8) = o;
}

// ---------- pool = l2norm(encoded.reshape(2048,256)) -> fp8 e4m3, 256B/row ----------
// Lane l owns chans [16l, 16l+16); byte c of row = chan c (little-endian).
__global__ __launch_bounds__(256) void pool_norm_kernel(
    const float* __restrict__ enc, uint* __restrict__ pool8) {
  const int tid = threadIdx.x;
  const int grp = tid >> 4, lane = tid & 15;
  const int r = blockIdx.x * 16 + grp;  // 0..2047
  const float* src = enc + (size_t)r * 256 + lane * 16;
  float4 v0 = *(const float4*)(src);
  float4 v1 = *(const float4*)(src + 4);
  float4 v2 = *(const float4*)(src + 8);
  float4 v3 = *(const float4*)(src + 12);
  float c[16] = {v0.x, v0.y, v0.z, v0.w, v1.x, v1.y, v1.z, v1.w,
                 v2.x, v2.y, v2.z, v2.w, v3.x, v3.y, v3.z, v3.w};
  float ss = 0.f;
#pragma unroll
  for (int i = 0; i < 16; ++i) ss = fmaf(c[i], c[i], ss);
  ss = qsum16(ss);
  const float inv = rsqrtf(ss);
  uint q[4];
#pragma unroll
  for (int i = 0; i < 4; ++i) {
    int u = __builtin_amdgcn_cvt_pk_fp8_f32(c[4 * i] * inv, c[4 * i + 1] * inv, 0, false);
    u = __builtin_amdgcn_cvt_pk_fp8_f32(c[4 * i + 2] * inv, c[4 * i + 3] * inv, u, true);
    q[i] = (uint)u;
  }
  *(uint4*)(pool8 + (size_t)r * 64 + lane * 4) = make_uint4(q[0], q[1], q[2], q[3]);
}

// ---------- z_hat[k] = ctx_rows @ W[k]^T via bf16 MFMA, f16-pair out ----------
__global__ __launch_bounds__(256) void zhat_gemm_kernel(
    const ushort* __restrict__ ctxb, const ushort* __restrict__ Wb,
    uint* __restrict__ Zp) {
  const int kk = blockIdx.z;
  const int Tk = 255 - kk, Nk = 8 * Tk;
  const int rowbase = blockIdx.y * 64;
  if (rowbase >= Nk) return;
  const int colbase = blockIdx.x * 128;

  __shared__ ushort As[64 * 40];   // row stride 40 bf16 (80 B, 16B-aligned)
  __shared__ ushort Bs[128 * 40];

  const int tid = threadIdx.x;
  const int arow = tid & 63;
  const int akseg = (tid >> 6) * 8;       // {0,8,16,24}
  int n = rowbase + arow;
  if (n >= Nk) n = Nk - 1;  // clamp (valid memory; result rows discarded)
  const int bb = n / Tk, tt = n - bb * Tk;
  const ushort* aptr = ctxb + ((size_t)(bb * 256 + tt)) * 512 + akseg;
  const int brow = tid & 127;
  const int bk0 = (tid >> 7) * 8;         // {0,8}
  const ushort* bptr = Wb + ((size_t)kk * 256 + colbase + brow) * 512 + bk0;

  const int wid = tid >> 6, lane = tid & 63;
  const int wm = wid >> 1, wn = wid & 1;
  const int l15 = lane & 15, l16 = lane >> 4;

  f32x4 acc[2][4];
#pragma unroll
  for (int i = 0; i < 2; ++i)
#pragma unroll
    for (int j = 0; j < 4; ++j) acc[i][j] = (f32x4){0.f, 0.f, 0.f, 0.f};

  const ushort* aread = &As[(wm * 32 + l15) * 40 + l16 * 8];
  const ushort* bread = &Bs[(wn * 64 + l15) * 40 + l16 * 8];

  for (int k0 = 0; k0 < 512; k0 += 32) {
    const uint4 av = *(const uint4*)(aptr + k0);
    const uint4 bv0 = *(const uint4*)(bptr + k0);
    const uint4 bv1 = *(const uint4*)(bptr + k0 + 16);
    __syncthreads();
    *(uint4*)&As[arow * 40 + akseg] = av;
    *(uint4*)&Bs[brow * 40 + bk0] = bv0;
    *(uint4*)&Bs[brow * 40 + bk0 + 16] = bv1;
    __syncthreads();
    short8 bf[4];
#pragma unroll
    for (int nb = 0; nb < 4; ++nb) bf[nb] = *(const short8*)(bread + nb * 16 * 40);
#pragma unroll
    for (int mb = 0; mb < 2; ++mb) {
      short8 af = *(const short8*)(aread + mb * 16 * 40);
#pragma unroll
      for (int nb = 0; nb < 4; ++nb)
        acc[mb][nb] = __builtin_amdgcn_mfma_f32_16x16x32_bf16(af, bf[nb], acc[mb][nb], 0, 0, 0);
    }
  }

  // Epilogue: uint u (in [0,128)) holds chans (32*(u>>4)+(u&15), +16).
#pragma unroll
  for (int mb = 0; mb < 2; ++mb) {
    const int row0 = rowbase + wm * 32 + mb * 16 + l16 * 4;
#pragma unroll
    for (int r = 0; r < 4; ++r) {
      const int row = row0 + r;
      if (row < Nk) {
        uint* zp = Zp + ((size_t)kk * 2040 + row) * 128 + (colbase >> 1) + wn * 32 + l15;
        zp[0]  = pkh(acc[mb][0][r], acc[mb][1][r]);
        zp[16] = pkh(acc[mb][2][r], acc[mb][3][r]);
      }
    }
  }
}

// ---------- loss: 16 lanes/row; fp8 pool gathers, double-buffered ----------
// dot of lane's 16 f32 z-chans with 16 fp8 pool chans (one uint4).
__device__ __forceinline__ float dot16_fp8(const float* __restrict__ z,
                                           const uint4 p) {
  const uint u[4] = {p.x, p.y, p.z, p.w};
  float d0 = 0.f, d1 = 0.f;
#pragma unroll
  for (int i = 0; i < 4; ++i) {
    const f32x2 a = __builtin_amdgcn_cvt_pk_f32_fp8(u[i], false);  // chans 4i+0,1
    const f32x2 b = __builtin_amdgcn_cvt_pk_f32_fp8(u[i], true);   // chans 4i+2,3
    d0 = fmaf(z[4 * i],     a.x, d0);
    d1 = fmaf(z[4 * i + 1], a.y, d1);
    d0 = fmaf(z[4 * i + 2], b.x, d0);
    d1 = fmaf(z[4 * i + 3], b.y, d1);
  }
  return d0 + d1;
}

#define LD1(P, IDX) P = *(const uint4*)(pb + (size_t)(IDX) * 64);
#define ACC1(S, P) S += exp2f(fmaf(qsum16(dot16_fp8(z, P)), sce, -OFFE));

__global__ __launch_bounds__(256) void loss_kernel(
    const uint* __restrict__ Zp, const uint* __restrict__ pool8,
    const int* __restrict__ neg_idx, float* __restrict__ acc) {
  const int kk = blockIdx.y;
  const int Tk = 255 - kk, Nk = 8 * Tk;
  const int tid = threadIdx.x;
  const int grp = tid >> 4, lane = tid & 15;
  const int n = blockIdx.x * 16 + grp;
  float row_loss = 0.f;
  if (n < Nk) {
    // z unpack: lane l owns chans [16l,16l+16): (l&1) half of uints [16*(l>>1), +16)
    const uint* zr = Zp + ((size_t)kk * 2040 + n) * 128 + (lane >> 1) * 16;
    uint qa[16];
    *(uint4*)(qa)      = *(const uint4*)(zr);
    *(uint4*)(qa + 4)  = *(const uint4*)(zr + 4);
    *(uint4*)(qa + 8)  = *(const uint4*)(zr + 8);
    *(uint4*)(qa + 12) = *(const uint4*)(zr + 12);
    const int sh = (lane & 1) * 16;
    float z[16];
    float ss = 0.f;
#pragma unroll
    for (int j = 0; j < 16; ++j) {
      const ushort hu = (ushort)(qa[j] >> sh);
      const float f = (float)__builtin_bit_cast(_Float16, hu);
      z[j] = f;
      ss = fmaf(f, f, ss);
    }
    ss = qsum16(ss);
    const float sce = rsqrtf(ss) * (INV_TEMP * L2E);  // logit(base2) = dot * sce

    const uint* pb = pool8 + lane * 4;
    const int bb = n / Tk, tt = n - bb * Tk;
    uint4 PP;
    LD1(PP, bb * 256 + tt + kk + 1)
    const float pose = qsum16(dot16_fp8(z, PP)) * sce;

    const int* ip = neg_idx + ((size_t)kk * 2040 + n) * 128;
    float s0 = 0.f, s1 = 0.f, s2 = 0.f, s3 = 0.f;
    uint4 A, B, C, D, E, F, G, H;
    {
      const int4 iv = *(const int4*)ip;
      LD1(A, iv.x) LD1(B, iv.y) LD1(C, iv.z) LD1(D, iv.w)
    }
    for (int j8 = 0; j8 < 16; ++j8) {
      {  // prefetch odd quad
        const int4 jv = *(const int4*)(ip + j8 * 8 + 4);
        LD1(E, jv.x) LD1(F, jv.y) LD1(G, jv.z) LD1(H, jv.w)
      }
      ACC1(s0, A) ACC1(s1, B) ACC1(s2, C) ACC1(s3, D)
      if (j8 < 15) {  // prefetch next even quad
        const int4 kv = *(const int4*)(ip + j8 * 8 + 8);
        LD1(A, kv.x) LD1(B, kv.y) LD1(C, kv.z) LD1(D, kv.w)
      }
      ACC1(s0, E) ACC1(s1, F) ACC1(s2, G) ACC1(s3, H)
    }
    const float ssum = (s0 + s1) + (s2 + s3) + exp2f(pose - OFFE);
    row_loss = LOGIT_MAX + 0.69314718f * (__log2f(ssum) - pose);
  }
  __shared__ float bl[16];
  if (lane == 0) bl[grp] = row_loss;
  __syncthreads();
  if (tid == 0) {
    float s = 0.f;
#pragma unroll
    for (int i = 0; i < 16; ++i) s += bl[i];
    atomicAdd(&acc[kk], s);
  }
}

__global__ void finalize_kernel(const float* __restrict__ acc,
                                float* __restrict__ out) {
  if (threadIdx.x == 0) {
    float tot = 0.f;
#pragma unroll
    for (int kk = 0; kk < 12; ++kk) tot += acc[kk] / (8.0f * (255 - kk));
    out[0] = tot / 12.0f;
  }
}

extern "C" void kernel_launch(void* const* d_in, const int* in_sizes, int n_in,
                              void* d_out, int out_size, void* d_ws, size_t ws_size,
                              hipStream_t stream) {
  const float* ctx = (const float*)d_in[0];   // (8,256,512)
  const float* enc = (const float*)d_in[1];   // (8,256,256)
  const float* W   = (const float*)d_in[2];   // (12,256,512)
  const int*   neg = (const int*)d_in[3];     // (12,2040,128)
  float* out = (float*)d_out;

  char* ws = (char*)d_ws;
  uint*   pool8 = (uint*)(ws);                      // 2048*256*1 = 524,288 B
  ushort* ctxb  = (ushort*)(ws + 524288);           // 2,097,152 B
  ushort* Wb    = (ushort*)(ws + 2621440);          // 3,145,728 B
  uint*   Zp    = (uint*)(ws + 5767168);            // 12*2040*128*4 = 12,533,760 B
  float*  acc   = (float*)(ws + 5767168 + 12533760);

  hipMemsetAsync(acc, 0, 12 * sizeof(float), stream);
  cvt_bf16_kernel<<<dim3(512), dim3(256), 0, stream>>>(ctx, ctxb);
  cvt_bf16_kernel<<<dim3(768), dim3(256), 0, stream>>>(W, Wb);
  pool_norm_kernel<<<dim3(128), dim3(256), 0, stream>>>(enc, pool8);
  zhat_gemm_kernel<<<dim3(2, 32, 12), dim3(256), 0, stream>>>(ctxb, Wb, Zp);
  loss_kernel<<<dim3(128, 12), dim3(256), 0, stream>>>(Zp, pool8, neg, acc);
  finalize_kernel<<<dim3(1), dim3(64), 0, stream>>>(acc, out);
}

// Round 7
// 74.531 us; speedup vs baseline: 3.9691x; 1.2835x over previous
//
#include <hip/hip_runtime.h>
#include <hip/hip_bf16.h>

typedef __attribute__((ext_vector_type(8))) short short8;
typedef __attribute__((ext_vector_type(4))) float f32x4;
typedef _Float16 __attribute__((ext_vector_type(2))) half2v;

#define INV_TEMP 14.285714285714286f
#define LOGIT_MAX 14.2857143f
#define L2E 1.44269504f
#define OFFE (LOGIT_MAX * L2E)

__device__ __forceinline__ ushort bf16c(float f) {
  uint u = __float_as_uint(f);
  uint r = (u + 0x7fffu + ((u >> 16) & 1u)) >> 16;
  return (ushort)r;
}
__device__ __forceinline__ uint pk2(float a, float b) {
  return (uint)bf16c(a) | ((uint)bf16c(b) << 16);
}
__device__ __forceinline__ uint pkh(float a, float b) {
  return __builtin_bit_cast(uint, __builtin_amdgcn_cvt_pkrtz(a, b));
}
__device__ __forceinline__ half2v h2(uint u) {
  return __builtin_bit_cast(half2v, u);
}
__device__ __forceinline__ float fdot2(half2v a, half2v b, float c) {
  return __builtin_amdgcn_fdot2(a, b, c, false);
}
__device__ __forceinline__ int sdot4_(uint a, uint b, int c) {
  return __builtin_amdgcn_sdot4((int)a, (int)b, c, false);
}

template <int CTRL>
__device__ __forceinline__ float dpp_add(float v) {
  const int x = __builtin_amdgcn_mov_dpp(__float_as_int(v), CTRL, 0xF, 0xF, true);
  return v + __int_as_float(x);
}
template <int CTRL>
__device__ __forceinline__ int dpp_addi(int v) {
  return v + __builtin_amdgcn_mov_dpp(v, CTRL, 0xF, 0xF, true);
}
__device__ __forceinline__ float qsum16(float v) {
  v = dpp_add<0xB1>(v);
  v = dpp_add<0x4E>(v);
  v = dpp_add<0x141>(v);
  v = dpp_add<0x140>(v);
  return v;
}
// sum over 8-lane group: xor1, xor2, then half-row mirror (crosses the quads)
__device__ __forceinline__ int qsum8i(int v) {
  v = dpp_addi<0xB1>(v);
  v = dpp_addi<0x4E>(v);
  v = dpp_addi<0x141>(v);
  return v;
}

// ---------- fp32 -> bf16 elementwise (8 per thread) ----------
__global__ __launch_bounds__(256) void cvt_bf16_kernel(
    const float* __restrict__ in, ushort* __restrict__ out) {
  const int i = blockIdx.x * 256 + threadIdx.x;
  const float4 a = *(const float4*)(in + (size_t)i * 8);
  const float4 b = *(const float4*)(in + (size_t)i * 8 + 4);
  const uint4 o = make_uint4(pk2(a.x, a.y), pk2(a.z, a.w), pk2(b.x, b.y), pk2(b.z, b.w));
  *(uint4*)(out + (size_t)i * 8) = o;
}

// ---------- pool = l2norm(encoded.reshape(2048,256)) -> int8 (x127), 256B/row ----------
// Byte c of row = chan c. Lane l owns chans [16l, 16l+16).
__global__ __launch_bounds__(256) void pool_norm_kernel(
    const float* __restrict__ enc, uint* __restrict__ pool8) {
  const int tid = threadIdx.x;
  const int grp = tid >> 4, lane = tid & 15;
  const int r = blockIdx.x * 16 + grp;  // 0..2047
  const float* src = enc + (size_t)r * 256 + lane * 16;
  float4 v0 = *(const float4*)(src);
  float4 v1 = *(const float4*)(src + 4);
  float4 v2 = *(const float4*)(src + 8);
  float4 v3 = *(const float4*)(src + 12);
  float c[16] = {v0.x, v0.y, v0.z, v0.w, v1.x, v1.y, v1.z, v1.w,
                 v2.x, v2.y, v2.z, v2.w, v3.x, v3.y, v3.z, v3.w};
  float ss = 0.f;
#pragma unroll
  for (int i = 0; i < 16; ++i) ss = fmaf(c[i], c[i], ss);
  ss = qsum16(ss);
  const float s127 = rsqrtf(ss) * 127.f;
  uint q[4];
#pragma unroll
  for (int i = 0; i < 4; ++i) {
    const int a = (int)rintf(c[4 * i] * s127);
    const int b = (int)rintf(c[4 * i + 1] * s127);
    const int cc = (int)rintf(c[4 * i + 2] * s127);
    const int d = (int)rintf(c[4 * i + 3] * s127);
    q[i] = (a & 255) | ((b & 255) << 8) | ((cc & 255) << 16) | ((uint)d << 24);
  }
  *(uint4*)(pool8 + (size_t)r * 64 + lane * 4) = make_uint4(q[0], q[1], q[2], q[3]);
}

// ---------- z_hat[k] = ctx_rows @ W[k]^T via bf16 MFMA, f16-pair out ----------
__global__ __launch_bounds__(256) void zhat_gemm_kernel(
    const ushort* __restrict__ ctxb, const ushort* __restrict__ Wb,
    uint* __restrict__ Zp) {
  const int kk = blockIdx.z;
  const int Tk = 255 - kk, Nk = 8 * Tk;
  const int rowbase = blockIdx.y * 64;
  if (rowbase >= Nk) return;
  const int colbase = blockIdx.x * 128;

  __shared__ ushort As[64 * 40];
  __shared__ ushort Bs[128 * 40];

  const int tid = threadIdx.x;
  const int arow = tid & 63;
  const int akseg = (tid >> 6) * 8;
  int n = rowbase + arow;
  if (n >= Nk) n = Nk - 1;
  const int bb = n / Tk, tt = n - bb * Tk;
  const ushort* aptr = ctxb + ((size_t)(bb * 256 + tt)) * 512 + akseg;
  const int brow = tid & 127;
  const int bk0 = (tid >> 7) * 8;
  const ushort* bptr = Wb + ((size_t)kk * 256 + colbase + brow) * 512 + bk0;

  const int wid = tid >> 6, lane = tid & 63;
  const int wm = wid >> 1, wn = wid & 1;
  const int l15 = lane & 15, l16 = lane >> 4;

  f32x4 acc[2][4];
#pragma unroll
  for (int i = 0; i < 2; ++i)
#pragma unroll
    for (int j = 0; j < 4; ++j) acc[i][j] = (f32x4){0.f, 0.f, 0.f, 0.f};

  const ushort* aread = &As[(wm * 32 + l15) * 40 + l16 * 8];
  const ushort* bread = &Bs[(wn * 64 + l15) * 40 + l16 * 8];

  for (int k0 = 0; k0 < 512; k0 += 32) {
    const uint4 av = *(const uint4*)(aptr + k0);
    const uint4 bv0 = *(const uint4*)(bptr + k0);
    const uint4 bv1 = *(const uint4*)(bptr + k0 + 16);
    __syncthreads();
    *(uint4*)&As[arow * 40 + akseg] = av;
    *(uint4*)&Bs[brow * 40 + bk0] = bv0;
    *(uint4*)&Bs[brow * 40 + bk0 + 16] = bv1;
    __syncthreads();
    short8 bf[4];
#pragma unroll
    for (int nb = 0; nb < 4; ++nb) bf[nb] = *(const short8*)(bread + nb * 16 * 40);
#pragma unroll
    for (int mb = 0; mb < 2; ++mb) {
      short8 af = *(const short8*)(aread + mb * 16 * 40);
#pragma unroll
      for (int nb = 0; nb < 4; ++nb)
        acc[mb][nb] = __builtin_amdgcn_mfma_f32_16x16x32_bf16(af, bf[nb], acc[mb][nb], 0, 0, 0);
    }
  }

  // uint u of row holds chans (32*(u>>4)+(u&15), +16)
#pragma unroll
  for (int mb = 0; mb < 2; ++mb) {
    const int row0 = rowbase + wm * 32 + mb * 16 + l16 * 4;
#pragma unroll
    for (int r = 0; r < 4; ++r) {
      const int row = row0 + r;
      if (row < Nk) {
        uint* zp = Zp + ((size_t)kk * 2040 + row) * 128 + (colbase >> 1) + wn * 32 + l15;
        zp[0]  = pkh(acc[mb][0][r], acc[mb][1][r]);
        zp[16] = pkh(acc[mb][2][r], acc[mb][3][r]);
      }
    }
  }
}

// ---------- loss: 8 lanes/row (lane owns 32 chans), int8 sdot4 ----------
__device__ __forceinline__ int dot32_i8(const uint* __restrict__ zq,
                                        const uint4 p0, const uint4 p1) {
  int d0 = 0, d1 = 0;
  d0 = sdot4_(zq[0], p0.x, d0); d1 = sdot4_(zq[1], p0.y, d1);
  d0 = sdot4_(zq[2], p0.z, d0); d1 = sdot4_(zq[3], p0.w, d1);
  d0 = sdot4_(zq[4], p1.x, d0); d1 = sdot4_(zq[5], p1.y, d1);
  d0 = sdot4_(zq[6], p1.z, d0); d1 = sdot4_(zq[7], p1.w, d1);
  return d0 + d1;
}

#define LDB(P, IDX) { const uint* p_ = pbase + (size_t)(uint)(IDX) * 64;        \
    P##0 = *(const uint4*)p_; P##1 = *(const uint4*)(p_ + 4); }
#define ACCB(S, P)                                                              \
  S += exp2f(fmaf((float)qsum8i(dot32_i8(zq, P##0, P##1)), sceq, -OFFE));

__global__ __launch_bounds__(256) void loss_kernel(
    const uint* __restrict__ Zp, const uint* __restrict__ pool8,
    const int* __restrict__ neg_idx, float* __restrict__ acc) {
  const int kk = blockIdx.y;
  const int Tk = 255 - kk, Nk = 8 * Tk;
  if ((int)(blockIdx.x * 32) >= Nk) return;
  const int tid = threadIdx.x;
  const int n = blockIdx.x * 32 + (tid >> 3);
  const int g = tid & 7;
  float row_loss = 0.f;
  if (n < Nk) {
    // lane g owns chans [32g, 32g+32) = Zp uints [16g, 16g+16): lo -> +0..15, hi -> +16..31
    const uint* zr = Zp + ((size_t)kk * 2040 + n) * 128 + g * 16;
    uint zu[16];
#pragma unroll
    for (int i = 0; i < 4; ++i) *(uint4*)(zu + 4 * i) = *(const uint4*)(zr + 4 * i);
    float ss = 0.f;
#pragma unroll
    for (int i = 0; i < 16; ++i) {
      const half2v h = h2(zu[i]);
      ss = fdot2(h, h, ss);
    }
    ss = dpp_add<0xB1>(ss); ss = dpp_add<0x4E>(ss); ss = dpp_add<0x141>(ss);
    const float s127 = rsqrtf(ss) * 127.f;
    // quantize: zq[t] = chans [32g+4t, 32g+4t+4) as int8
    uint zq[8];
#pragma unroll
    for (int t = 0; t < 8; ++t) {
      float e0, e1, e2, e3;
      if (t < 4) {
        e0 = (float)h2(zu[4 * t]).x;     e1 = (float)h2(zu[4 * t + 1]).x;
        e2 = (float)h2(zu[4 * t + 2]).x; e3 = (float)h2(zu[4 * t + 3]).x;
      } else {
        e0 = (float)h2(zu[4 * t - 16]).y; e1 = (float)h2(zu[4 * t - 15]).y;
        e2 = (float)h2(zu[4 * t - 14]).y; e3 = (float)h2(zu[4 * t - 13]).y;
      }
      const int a = (int)rintf(e0 * s127), b = (int)rintf(e1 * s127);
      const int c = (int)rintf(e2 * s127), d = (int)rintf(e3 * s127);
      zq[t] = (a & 255) | ((b & 255) << 8) | ((c & 255) << 16) | ((uint)d << 24);
    }
    // exact norm of quantized z
    int nq = 0;
#pragma unroll
    for (int t = 0; t < 8; ++t) nq = sdot4_(zq[t], zq[t], nq);
    nq = qsum8i(nq);
    const float sceq = (INV_TEMP * L2E) / (sqrtf((float)nq) * 127.f);

    const uint* pbase = pool8 + g * 8;
    const int bb = n / Tk, tt = n - bb * Tk;
    uint4 A0, A1, B0, B1, C0, C1, D0, D1, E0, E1, F0, F1, G0, G1, H0, H1;
    LDB(A, bb * 256 + tt + kk + 1)
    const float pose = (float)qsum8i(dot32_i8(zq, A0, A1)) * sceq;

    const int* ip = neg_idx + ((size_t)kk * 2040 + n) * 128;
    float s0 = 0.f, s1 = 0.f, s2 = 0.f, s3 = 0.f;
    {
      const int4 iv = *(const int4*)ip;
      LDB(A, iv.x) LDB(B, iv.y) LDB(C, iv.z) LDB(D, iv.w)
    }
    for (int j8 = 0; j8 < 16; ++j8) {
      {  // prefetch odd quad
        const int4 jv = *(const int4*)(ip + j8 * 8 + 4);
        LDB(E, jv.x) LDB(F, jv.y) LDB(G, jv.z) LDB(H, jv.w)
      }
      ACCB(s0, A) ACCB(s1, B) ACCB(s2, C) ACCB(s3, D)
      if (j8 < 15) {  // prefetch next even quad
        const int4 kv = *(const int4*)(ip + j8 * 8 + 8);
        LDB(A, kv.x) LDB(B, kv.y) LDB(C, kv.z) LDB(D, kv.w)
      }
      ACCB(s0, E) ACCB(s1, F) ACCB(s2, G) ACCB(s3, H)
    }
    const float ssum = (s0 + s1) + (s2 + s3) + exp2f(pose - OFFE);
    row_loss = LOGIT_MAX + 0.69314718f * (__log2f(ssum) - pose);
  }
  // row_loss uniform within 8-lane group; row_mirror sums the two groups per 16 lanes
  const float v = dpp_add<0x140>(row_loss);
  __shared__ float bl[16];
  if ((tid & 15) == 0) bl[tid >> 4] = v;
  __syncthreads();
  if (tid == 0) {
    float s = 0.f;
#pragma unroll
    for (int i = 0; i < 16; ++i) s += bl[i];
    atomicAdd(&acc[kk], s);
  }
}

__global__ void finalize_kernel(const float* __restrict__ acc,
                                float* __restrict__ out) {
  if (threadIdx.x == 0) {
    float tot = 0.f;
#pragma unroll
    for (int kk = 0; kk < 12; ++kk) tot += acc[kk] / (8.0f * (255 - kk));
    out[0] = tot / 12.0f;
  }
}

extern "C" void kernel_launch(void* const* d_in, const int* in_sizes, int n_in,
                              void* d_out, int out_size, void* d_ws, size_t ws_size,
                              hipStream_t stream) {
  const float* ctx = (const float*)d_in[0];   // (8,256,512)
  const float* enc = (const float*)d_in[1];   // (8,256,256)
  const float* W   = (const float*)d_in[2];   // (12,256,512)
  const int*   neg = (const int*)d_in[3];     // (12,2040,128)
  float* out = (float*)d_out;

  char* ws = (char*)d_ws;
  uint*   pool8 = (uint*)(ws);                      // 2048*64*4 = 524,288 B
  ushort* ctxb  = (ushort*)(ws + 524288);           // 2,097,152 B
  ushort* Wb    = (ushort*)(ws + 2621440);          // 3,145,728 B
  uint*   Zp    = (uint*)(ws + 5767168);            // 12*2040*128*4 = 12,533,760 B
  float*  acc   = (float*)(ws + 5767168 + 12533760);

  hipMemsetAsync(acc, 0, 12 * sizeof(float), stream);
  cvt_bf16_kernel<<<dim3(512), dim3(256), 0, stream>>>(ctx, ctxb);
  cvt_bf16_kernel<<<dim3(768), dim3(256), 0, stream>>>(W, Wb);
  pool_norm_kernel<<<dim3(128), dim3(256), 0, stream>>>(enc, pool8);
  zhat_gemm_kernel<<<dim3(2, 32, 12), dim3(256), 0, stream>>>(ctxb, Wb, Zp);
  loss_kernel<<<dim3(64, 12), dim3(256), 0, stream>>>(Zp, pool8, neg, acc);
  finalize_kernel<<<dim3(1), dim3(64), 0, stream>>>(acc, out);
}

// Round 8
// 70.168 us; speedup vs baseline: 4.2159x; 1.0622x over previous
//
#include <hip/hip_runtime.h>
#include <hip/hip_bf16.h>

typedef __attribute__((ext_vector_type(8))) short short8;
typedef __attribute__((ext_vector_type(4))) float f32x4;
typedef _Float16 __attribute__((ext_vector_type(2))) half2v;

#define INV_TEMP 14.285714285714286f
#define LOGIT_MAX 14.2857143f
#define L2E 1.44269504f
#define OFFE (LOGIT_MAX * L2E)

__device__ __forceinline__ ushort bf16c(float f) {
  uint u = __float_as_uint(f);
  uint r = (u + 0x7fffu + ((u >> 16) & 1u)) >> 16;
  return (ushort)r;
}
__device__ __forceinline__ uint pk2(float a, float b) {
  return (uint)bf16c(a) | ((uint)bf16c(b) << 16);
}
__device__ __forceinline__ uint pkh(float a, float b) {
  return __builtin_bit_cast(uint, __builtin_amdgcn_cvt_pkrtz(a, b));
}
__device__ __forceinline__ half2v h2(uint u) {
  return __builtin_bit_cast(half2v, u);
}
__device__ __forceinline__ float fdot2(half2v a, half2v b, float c) {
  return __builtin_amdgcn_fdot2(a, b, c, false);
}
__device__ __forceinline__ int sdot4_(uint a, uint b, int c) {
  return __builtin_amdgcn_sdot4((int)a, (int)b, c, false);
}

template <int CTRL>
__device__ __forceinline__ float dpp_add(float v) {
  const int x = __builtin_amdgcn_mov_dpp(__float_as_int(v), CTRL, 0xF, 0xF, true);
  return v + __int_as_float(x);
}
template <int CTRL>
__device__ __forceinline__ int dpp_addi(int v) {
  return v + __builtin_amdgcn_mov_dpp(v, CTRL, 0xF, 0xF, true);
}
__device__ __forceinline__ float qsum16(float v) {
  v = dpp_add<0xB1>(v);
  v = dpp_add<0x4E>(v);
  v = dpp_add<0x141>(v);
  v = dpp_add<0x140>(v);
  return v;
}
// sum over 8 contiguous lanes (quads + half-row mirror)
__device__ __forceinline__ int qsum8i(int v) {
  v = dpp_addi<0xB1>(v);
  v = dpp_addi<0x4E>(v);
  v = dpp_addi<0x141>(v);
  return v;
}

// ---------- fp32 -> bf16 for ctx (blocks [0,512)) and W (blocks [512,1280)) ----------
__global__ __launch_bounds__(256) void cvt_bf16_kernel(
    const float* __restrict__ ctx, const float* __restrict__ W,
    ushort* __restrict__ ctxb, ushort* __restrict__ Wb) {
  const int bid = blockIdx.x;
  const float* in;
  ushort* out;
  size_t i;
  if (bid < 512) { in = ctx; out = ctxb; i = (size_t)bid * 256 + threadIdx.x; }
  else           { in = W;   out = Wb;   i = (size_t)(bid - 512) * 256 + threadIdx.x; }
  const float4 a = *(const float4*)(in + i * 8);
  const float4 b = *(const float4*)(in + i * 8 + 4);
  const uint4 o = make_uint4(pk2(a.x, a.y), pk2(a.z, a.w), pk2(b.x, b.y), pk2(b.z, b.w));
  *(uint4*)(out + i * 8) = o;
}

// ---------- pool = l2norm(encoded.reshape(2048,256)) -> int8 (x127), 256B/row ----------
// Byte c of row = chan c. Also zeroes acc[0..11] (runs before loss_kernel in-stream).
__global__ __launch_bounds__(256) void pool_norm_kernel(
    const float* __restrict__ enc, uint* __restrict__ pool8,
    float* __restrict__ acc) {
  const int tid = threadIdx.x;
  if (blockIdx.x == 0 && tid < 12) acc[tid] = 0.f;
  const int grp = tid >> 4, lane = tid & 15;
  const int r = blockIdx.x * 16 + grp;  // 0..2047
  const float* src = enc + (size_t)r * 256 + lane * 16;
  float4 v0 = *(const float4*)(src);
  float4 v1 = *(const float4*)(src + 4);
  float4 v2 = *(const float4*)(src + 8);
  float4 v3 = *(const float4*)(src + 12);
  float c[16] = {v0.x, v0.y, v0.z, v0.w, v1.x, v1.y, v1.z, v1.w,
                 v2.x, v2.y, v2.z, v2.w, v3.x, v3.y, v3.z, v3.w};
  float ss = 0.f;
#pragma unroll
  for (int i = 0; i < 16; ++i) ss = fmaf(c[i], c[i], ss);
  ss = qsum16(ss);
  const float s127 = rsqrtf(ss) * 127.f;
  uint q[4];
#pragma unroll
  for (int i = 0; i < 4; ++i) {
    const int a = (int)rintf(c[4 * i] * s127);
    const int b = (int)rintf(c[4 * i + 1] * s127);
    const int cc = (int)rintf(c[4 * i + 2] * s127);
    const int d = (int)rintf(c[4 * i + 3] * s127);
    q[i] = (a & 255) | ((b & 255) << 8) | ((cc & 255) << 16) | ((uint)d << 24);
  }
  *(uint4*)(pool8 + (size_t)r * 64 + lane * 4) = make_uint4(q[0], q[1], q[2], q[3]);
}

// ---------- z_hat[k] = ctx_rows @ W[k]^T via bf16 MFMA, f16-pair out ----------
__global__ __launch_bounds__(256) void zhat_gemm_kernel(
    const ushort* __restrict__ ctxb, const ushort* __restrict__ Wb,
    uint* __restrict__ Zp) {
  const int kk = blockIdx.z;
  const int Tk = 255 - kk, Nk = 8 * Tk;
  const int rowbase = blockIdx.y * 64;
  if (rowbase >= Nk) return;
  const int colbase = blockIdx.x * 128;

  __shared__ ushort As[64 * 40];
  __shared__ ushort Bs[128 * 40];

  const int tid = threadIdx.x;
  const int arow = tid & 63;
  const int akseg = (tid >> 6) * 8;
  int n = rowbase + arow;
  if (n >= Nk) n = Nk - 1;
  const int bb = n / Tk, tt = n - bb * Tk;
  const ushort* aptr = ctxb + ((size_t)(bb * 256 + tt)) * 512 + akseg;
  const int brow = tid & 127;
  const int bk0 = (tid >> 7) * 8;
  const ushort* bptr = Wb + ((size_t)kk * 256 + colbase + brow) * 512 + bk0;

  const int wid = tid >> 6, lane = tid & 63;
  const int wm = wid >> 1, wn = wid & 1;
  const int l15 = lane & 15, l16 = lane >> 4;

  f32x4 acc[2][4];
#pragma unroll
  for (int i = 0; i < 2; ++i)
#pragma unroll
    for (int j = 0; j < 4; ++j) acc[i][j] = (f32x4){0.f, 0.f, 0.f, 0.f};

  const ushort* aread = &As[(wm * 32 + l15) * 40 + l16 * 8];
  const ushort* bread = &Bs[(wn * 64 + l15) * 40 + l16 * 8];

  for (int k0 = 0; k0 < 512; k0 += 32) {
    const uint4 av = *(const uint4*)(aptr + k0);
    const uint4 bv0 = *(const uint4*)(bptr + k0);
    const uint4 bv1 = *(const uint4*)(bptr + k0 + 16);
    __syncthreads();
    *(uint4*)&As[arow * 40 + akseg] = av;
    *(uint4*)&Bs[brow * 40 + bk0] = bv0;
    *(uint4*)&Bs[brow * 40 + bk0 + 16] = bv1;
    __syncthreads();
    short8 bf[4];
#pragma unroll
    for (int nb = 0; nb < 4; ++nb) bf[nb] = *(const short8*)(bread + nb * 16 * 40);
#pragma unroll
    for (int mb = 0; mb < 2; ++mb) {
      short8 af = *(const short8*)(aread + mb * 16 * 40);
#pragma unroll
      for (int nb = 0; nb < 4; ++nb)
        acc[mb][nb] = __builtin_amdgcn_mfma_f32_16x16x32_bf16(af, bf[nb], acc[mb][nb], 0, 0, 0);
    }
  }

  // uint u of row holds chans (32*(u>>4)+(u&15), +16)
#pragma unroll
  for (int mb = 0; mb < 2; ++mb) {
    const int row0 = rowbase + wm * 32 + mb * 16 + l16 * 4;
#pragma unroll
    for (int r = 0; r < 4; ++r) {
      const int row = row0 + r;
      if (row < Nk) {
        uint* zp = Zp + ((size_t)kk * 2040 + row) * 128 + (colbase >> 1) + wn * 32 + l15;
        zp[0]  = pkh(acc[mb][0][r], acc[mb][1][r]);
        zp[16] = pkh(acc[mb][2][r], acc[mb][3][r]);
      }
    }
  }
}

// ---------- loss: 16 lanes/row = 2 neg-halves x 8 chan-lanes, int8 sdot4 ----------
__device__ __forceinline__ int dot32_i8(const uint* __restrict__ zq,
                                        const uint4 p0, const uint4 p1) {
  int d0 = 0, d1 = 0;
  d0 = sdot4_(zq[0], p0.x, d0); d1 = sdot4_(zq[1], p0.y, d1);
  d0 = sdot4_(zq[2], p0.z, d0); d1 = sdot4_(zq[3], p0.w, d1);
  d0 = sdot4_(zq[4], p1.x, d0); d1 = sdot4_(zq[5], p1.y, d1);
  d0 = sdot4_(zq[6], p1.z, d0); d1 = sdot4_(zq[7], p1.w, d1);
  return d0 + d1;
}

#define LDB(P, IDX) { const uint* p_ = pbase + (size_t)(uint)(IDX) * 64;        \
    P##0 = *(const uint4*)p_; P##1 = *(const uint4*)(p_ + 4); }
#define ACCB(S, P)                                                              \
  S += exp2f(fmaf((float)qsum8i(dot32_i8(zq, P##0, P##1)), sceq, -OFFE));

__global__ __launch_bounds__(256) void loss_kernel(
    const uint* __restrict__ Zp, const uint* __restrict__ pool8,
    const int* __restrict__ neg_idx, float* __restrict__ acc) {
  const int kk = blockIdx.y;
  const int Tk = 255 - kk, Nk = 8 * Tk;
  if ((int)(blockIdx.x * 16) >= Nk) return;
  const int tid = threadIdx.x;
  const int n = blockIdx.x * 16 + (tid >> 4);
  const int l = tid & 15;
  const int h = l >> 3;   // neg half: negs [64h, 64h+64)
  const int g = l & 7;    // chan chunk: chans [32g, 32g+32)
  float row_loss = 0.f;
  if (n < Nk) {
    // lane's chans [32g,32g+32) = Zp uints [16g,16g+16): lo -> +0..15, hi -> +16..31
    const uint* zr = Zp + ((size_t)kk * 2040 + n) * 128 + g * 16;
    uint zu[16];
#pragma unroll
    for (int i = 0; i < 4; ++i) *(uint4*)(zu + 4 * i) = *(const uint4*)(zr + 4 * i);
    float ss = 0.f;
#pragma unroll
    for (int i = 0; i < 16; ++i) {
      const half2v hv = h2(zu[i]);
      ss = fdot2(hv, hv, ss);
    }
    ss = dpp_add<0xB1>(ss); ss = dpp_add<0x4E>(ss); ss = dpp_add<0x141>(ss);
    const float s127 = rsqrtf(ss) * 127.f;
    uint zq[8];
#pragma unroll
    for (int t = 0; t < 8; ++t) {
      float e0, e1, e2, e3;
      if (t < 4) {
        e0 = (float)h2(zu[4 * t]).x;     e1 = (float)h2(zu[4 * t + 1]).x;
        e2 = (float)h2(zu[4 * t + 2]).x; e3 = (float)h2(zu[4 * t + 3]).x;
      } else {
        e0 = (float)h2(zu[4 * t - 16]).y; e1 = (float)h2(zu[4 * t - 15]).y;
        e2 = (float)h2(zu[4 * t - 14]).y; e3 = (float)h2(zu[4 * t - 13]).y;
      }
      const int a = (int)rintf(e0 * s127), b = (int)rintf(e1 * s127);
      const int c = (int)rintf(e2 * s127), d = (int)rintf(e3 * s127);
      zq[t] = (a & 255) | ((b & 255) << 8) | ((c & 255) << 16) | ((uint)d << 24);
    }
    // exact norm of quantized z
    int nq = 0;
#pragma unroll
    for (int t = 0; t < 8; ++t) nq = sdot4_(zq[t], zq[t], nq);
    nq = qsum8i(nq);
    const float sceq = (INV_TEMP * L2E) / (sqrtf((float)nq) * 127.f);

    const uint* pbase = pool8 + g * 8;
    const int bb = n / Tk, tt = n - bb * Tk;
    uint4 A0, A1, B0, B1, C0, C1, D0, D1, E0, E1, F0, F1, G0, G1, H0, H1;
    LDB(A, bb * 256 + tt + kk + 1)
    const float pose = (float)qsum8i(dot32_i8(zq, A0, A1)) * sceq;

    // this half's 64 negs, 4+4 double-buffered
    const int* ip = neg_idx + ((size_t)kk * 2040 + n) * 128 + h * 64;
    float s0 = 0.f, s1 = 0.f, s2 = 0.f, s3 = 0.f;
    {
      const int4 iv = *(const int4*)ip;
      LDB(A, iv.x) LDB(B, iv.y) LDB(C, iv.z) LDB(D, iv.w)
    }
    for (int j8 = 0; j8 < 8; ++j8) {
      {  // prefetch odd quad
        const int4 jv = *(const int4*)(ip + j8 * 8 + 4);
        LDB(E, jv.x) LDB(F, jv.y) LDB(G, jv.z) LDB(H, jv.w)
      }
      ACCB(s0, A) ACCB(s1, B) ACCB(s2, C) ACCB(s3, D)
      if (j8 < 7) {  // prefetch next even quad
        const int4 kv = *(const int4*)(ip + j8 * 8 + 8);
        LDB(A, kv.x) LDB(B, kv.y) LDB(C, kv.z) LDB(D, kv.w)
      }
      ACCB(s0, E) ACCB(s1, F) ACCB(s2, G) ACCB(s3, H)
    }
    // combine the two halves: group-uniform partial, row_mirror crosses (h,g)<->(1-h,7-g)
    float sl = (s0 + s1) + (s2 + s3);
    sl = dpp_add<0x140>(sl);
    const float ssum = sl + exp2f(pose - OFFE);
    row_loss = LOGIT_MAX + 0.69314718f * (__log2f(ssum) - pose);
  }
  __shared__ float bl[16];
  if (l == 0) bl[tid >> 4] = row_loss;
  __syncthreads();
  if (tid == 0) {
    float s = 0.f;
#pragma unroll
    for (int i = 0; i < 16; ++i) s += bl[i];
    atomicAdd(&acc[kk], s);
  }
}

__global__ void finalize_kernel(const float* __restrict__ acc,
                                float* __restrict__ out) {
  if (threadIdx.x == 0) {
    float tot = 0.f;
#pragma unroll
    for (int kk = 0; kk < 12; ++kk) tot += acc[kk] / (8.0f * (255 - kk));
    out[0] = tot / 12.0f;
  }
}

extern "C" void kernel_launch(void* const* d_in, const int* in_sizes, int n_in,
                              void* d_out, int out_size, void* d_ws, size_t ws_size,
                              hipStream_t stream) {
  const float* ctx = (const float*)d_in[0];   // (8,256,512)
  const float* enc = (const float*)d_in[1];   // (8,256,256)
  const float* W   = (const float*)d_in[2];   // (12,256,512)
  const int*   neg = (const int*)d_in[3];     // (12,2040,128)
  float* out = (float*)d_out;

  char* ws = (char*)d_ws;
  uint*   pool8 = (uint*)(ws);                      // 524,288 B
  ushort* ctxb  = (ushort*)(ws + 524288);           // 2,097,152 B
  ushort* Wb    = (ushort*)(ws + 2621440);          // 3,145,728 B
  uint*   Zp    = (uint*)(ws + 5767168);            // 12,533,760 B
  float*  acc   = (float*)(ws + 5767168 + 12533760);

  cvt_bf16_kernel<<<dim3(1280), dim3(256), 0, stream>>>(ctx, W, ctxb, Wb);
  pool_norm_kernel<<<dim3(128), dim3(256), 0, stream>>>(enc, pool8, acc);
  zhat_gemm_kernel<<<dim3(2, 32, 12), dim3(256), 0, stream>>>(ctxb, Wb, Zp);
  loss_kernel<<<dim3(128, 12), dim3(256), 0, stream>>>(Zp, pool8, neg, acc);
  finalize_kernel<<<dim3(1), dim3(64), 0, stream>>>(acc, out);
}